// Round 14
// baseline (529.627 us; speedup 1.0000x reference)
//
#include <hip/hip_runtime.h>
#include <math.h>

#define NN     100000
#define NE     1600000
#define FEAT   128
#define GQ     4
#define NL     3
#define NGR    64
#define NCLS   10
#define KSPL   512
#define NKS    10            /* K-steps of 64 (640 total) */
#define BM     32            /* nodes per block (256 threads, 4 waves: 2 rowgrp x 2 colgrp) */
#define NB     1563          /* dst buckets of 64 nodes: ceil(NN/64) */
#define NCHUNK 256
#define CHUNK  6250          /* NE / NCHUNK */
#define TILE   1024
#define NT     ((NN + TILE - 1) / TILE)   /* 98 scan tiles */
#define WSTRIDE (NKS*8*2*512)             /* 81920 ushorts per layer */

typedef __attribute__((ext_vector_type(8))) short short8;
typedef __attribute__((ext_vector_type(4))) float floatx4;
typedef __attribute__((ext_vector_type(4))) uint uintx4;

__device__ __forceinline__ float fsilu(float x){ return x / (1.f + __expf(-x)); }
__device__ __forceinline__ ushort f2bf(float f){
  uint u = __builtin_bit_cast(uint, f);
  return (ushort)((u + 0x7FFFu + ((u >> 16) & 1u)) >> 16);
}
__device__ __forceinline__ float bf2f(ushort h){ return __builtin_bit_cast(float, ((uint)h) << 16); }
__device__ __forceinline__ uint bu(float f){ return __builtin_bit_cast(uint, f); }
__device__ __forceinline__ uint pkbf(float lo, float hi){
  return __builtin_amdgcn_perm(bu(hi), bu(lo), 0x07060302u);  // truncating bf16x2 pack
}

// ---------------- small utility kernels ----------------
__global__ __launch_bounds__(256) void k_zero_i(int* __restrict__ p, int n){
  int i = blockIdx.x*256 + threadIdx.x; if (i < n) p[i] = 0;
}
__global__ __launch_bounds__(256) void k_zero_f(float* __restrict__ p, int n){
  int i = blockIdx.x*256 + threadIdx.x; if (i < n) p[i] = 0.f;
}
__global__ __launch_bounds__(256) void k_hist(const int* __restrict__ dst, int* __restrict__ hist, int ne){
  int e = blockIdx.x*256 + threadIdx.x; if (e < ne) atomicAdd(&hist[dst[e]], 1);
}

// ---- hierarchical exclusive scan over hist[NN] -> rp, dinv ----
__global__ __launch_bounds__(256) void k_scan_a(const int* __restrict__ hist, int* __restrict__ tsum){
  __shared__ int red[4];
  const int base = blockIdx.x * TILE;
  int s = 0;
  #pragma unroll
  for (int j = 0; j < 4; ++j){
    int idx = base + threadIdx.x + j*256;
    if (idx < NN) s += hist[idx];
  }
  #pragma unroll
  for (int off = 32; off; off >>= 1) s += __shfl_down(s, off);
  if ((threadIdx.x & 63) == 0) red[threadIdx.x >> 6] = s;
  __syncthreads();
  if (threadIdx.x == 0) tsum[blockIdx.x] = red[0] + red[1] + red[2] + red[3];
}

__global__ __launch_bounds__(128) void k_scan_b(const int* __restrict__ tsum,
                                                int* __restrict__ toff, int* __restrict__ rpN){
  __shared__ int lds[128];
  const int tid = threadIdx.x;
  int v = (tid < NT) ? tsum[tid] : 0;
  lds[tid] = v; __syncthreads();
  for (int off = 1; off < 128; off <<= 1){
    int u = (tid >= off) ? lds[tid - off] : 0;
    __syncthreads();
    lds[tid] += u;
    __syncthreads();
  }
  if (tid < NT) toff[tid] = lds[tid] - v;
  if (tid == NT - 1) *rpN = lds[tid];
}

__global__ __launch_bounds__(256) void k_scan_c(const int* __restrict__ hist,
                                                const int* __restrict__ toff,
                                                int* __restrict__ rp,
                                                float* __restrict__ dinv){
  __shared__ int lds[256];
  const int tid = threadIdx.x;
  const int base = blockIdx.x * TILE + tid*4;
  int h[4]; int s = 0;
  #pragma unroll
  for (int j = 0; j < 4; ++j){ int idx = base + j; h[j] = (idx < NN) ? hist[idx] : 0; s += h[j]; }
  lds[tid] = s; __syncthreads();
  for (int off = 1; off < 256; off <<= 1){
    int u = (tid >= off) ? lds[tid - off] : 0;
    __syncthreads();
    lds[tid] += u;
    __syncthreads();
  }
  int run = toff[blockIdx.x] + lds[tid] - s;
  #pragma unroll
  for (int j = 0; j < 4; ++j){
    int idx = base + j;
    if (idx < NN){
      rp[idx] = run; run += h[j];
      dinv[idx] = rsqrtf((float)h[j] + 1.f);
    }
  }
}

// ---- chunk-private binning: each block bins its 6250 edges by dst>>6 into its own region ----
// edge packed as (src<<6) | (dst&63)
__global__ __launch_bounds__(256) void k_binA(const int* __restrict__ src, const int* __restrict__ dst,
                                              uint* __restrict__ priv, int* __restrict__ seg){
  __shared__ int hist[NB];
  __shared__ int cur[NB];
  __shared__ int scanbuf[256];
  const int c = blockIdx.x, tid = threadIdx.x;
  const size_t e0 = (size_t)c * CHUNK;
  for (int i = tid; i < NB; i += 256) hist[i] = 0;
  __syncthreads();
  for (int i = tid; i < CHUNK; i += 256) atomicAdd(&hist[dst[e0+i] >> 6], 1);
  __syncthreads();
  int loc[7]; int s = 0;
  const int base = tid * 7;
  #pragma unroll
  for (int j = 0; j < 7; ++j){ int idx = base+j; int v = (idx < NB) ? hist[idx] : 0; loc[j] = s; s += v; }
  scanbuf[tid] = s;
  __syncthreads();
  for (int off = 1; off < 256; off <<= 1){
    int u = (tid >= off) ? scanbuf[tid-off] : 0;
    __syncthreads();
    scanbuf[tid] += u;
    __syncthreads();
  }
  const int run = scanbuf[tid] - s;
  #pragma unroll
  for (int j = 0; j < 7; ++j){
    int idx = base+j;
    if (idx < NB){ int st = run + loc[j]; seg[c*(NB+1)+idx] = st; cur[idx] = st; }
  }
  if (tid == 0) seg[c*(NB+1)+NB] = CHUNK;
  __syncthreads();
  for (int i = tid; i < CHUNK; i += 256){
    const uint ss = (uint)src[e0+i], dd = (uint)dst[e0+i];
    const int p = atomicAdd(&cur[dd >> 6], 1);
    priv[(size_t)c*CHUNK + p] = (ss << 6) | (dd & 63u);
  }
}

// per bucket: scatter chunk-private edges into dst-node-sorted col via rp cursors
__global__ __launch_bounds__(256) void k_gathE2(const uint* __restrict__ priv, const int* __restrict__ seg,
                                                const int* __restrict__ rp, int* __restrict__ col){
  __shared__ int cur[64];
  const int b = blockIdx.x, tid = threadIdx.x;
  const int n0 = b * 64;
  if (tid < 64){
    const int idx = n0 + tid;
    cur[tid] = rp[(idx < NN) ? idx : NN];
  }
  __syncthreads();
  const int c = tid;
  const int s0 = seg[c*(NB+1) + b], s1 = seg[c*(NB+1) + b + 1];
  const size_t pbase = (size_t)c*CHUNK;
  for (int i = s0; i < s1; ++i){
    const uint e = priv[pbase + i];
    const int p = atomicAdd(&cur[e & 63u], 1);
    col[p] = (int)(e >> 6);
  }
}

// weights -> bf16 in per-lane MFMA fragment layout:
// frag id = q*16 + nr*2 + ks ; wimg[frag][lane*8+j] = W[col][k]
//   col = nr*16+(lane&15), k = q*64+ks*32+(lane>>4)*8+j
__global__ __launch_bounds__(256) void k_wprep(const float* __restrict__ sW, const float* __restrict__ bW,
                                               ushort* __restrict__ wimg){
  int idx = blockIdx.x*256 + threadIdx.x;
  if (idx >= NL*WSTRIDE) return;
  const int j    = idx & 7;
  const int lane = (idx >> 3) & 63;
  const int ks   = (idx >> 9) & 1;
  const int nr   = (idx >> 10) & 7;
  const int qq   = (idx >> 13) % NKS;
  const int l    = idx / (NKS << 13);
  const int colc = nr*16 + (lane & 15);
  const int kg   = qq*64 + ks*32 + (lane >> 4)*8 + j;
  const float v  = (kg < KSPL) ? sW[((size_t)l*FEAT + colc)*KSPL + kg]
                               : bW[((size_t)l*FEAT + colc)*FEAT + (kg - KSPL)];
  wimg[idx] = f2bf(v);
}

// ---------------- FKAN transform: 4 waves (2 rowgrp x 2 colgrp), acc[4], low reg state ----------------
template <typename TIn>
__global__ __launch_bounds__(256) void k_fkan(
    const TIn* __restrict__ xin,            // [NN][128] fp32 or bf16(ushort)
    const ushort* __restrict__ wimg,        // this layer's fragment image (L2-resident)
    const float* __restrict__ ln_s, const float* __restrict__ ln_b,
    const float* __restrict__ sb, const float* __restrict__ bb,
    const float* __restrict__ dinv,
    ushort* __restrict__ hprime)
{
  __shared__ char xb[BM*256];          // x bf16 [32][128], xor-swizzled rows (8 KB)
  __shared__ float2 rstat[BM];         // per-row (mean, rsqrt)
  __shared__ float lnS[128], lnB[128], sbias[128];

  const int tid  = threadIdx.x;
  const int lane = tid & 63, wv = tid >> 6;
  const int node0 = blockIdx.x * BM;   // NN % 32 == 0: no guards

  if (tid < 128){ lnS[tid] = ln_s[tid]; lnB[tid] = ln_b[tid]; sbias[tid] = sb[tid] + bb[tid]; }

  // ---- LN stats phase: 8 threads per node, 16 feats each; stage bf16 x in LDS ----
  const int lm = tid >> 3, part = tid & 7;
  const int node = node0 + lm;
  const uint swl = ((uint)(lm & 7)) << 4;
  char* xrow_w = xb + lm*256;
  float s1 = 0.f, s2 = 0.f;
  if constexpr (sizeof(TIn) == 4){
    const float4* xr = (const float4*)((const float*)xin + (size_t)node*FEAT + part*16);
    #pragma unroll
    for (int j = 0; j < 2; ++j){
      const float4 a = xr[2*j], b = xr[2*j+1];
      s1 += a.x+a.y+a.z+a.w + b.x+b.y+b.z+b.w;
      s2 += a.x*a.x+a.y*a.y+a.z*a.z+a.w*a.w + b.x*b.x+b.y*b.y+b.z*b.z+b.w*b.w;
      uintx4 pk;
      pk.x = pkbf(a.x, a.y); pk.y = pkbf(a.z, a.w);
      pk.z = pkbf(b.x, b.y); pk.w = pkbf(b.z, b.w);
      *(uintx4*)(xrow_w + (((uint)(part*32 + j*16)) ^ swl)) = pk;
    }
  } else {
    const uintx4* xr = (const uintx4*)((const ushort*)xin + (size_t)node*FEAT + part*16);
    #pragma unroll
    for (int j = 0; j < 2; ++j){
      const uintx4 v = xr[j];
      #pragma unroll
      for (int w = 0; w < 4; ++w){
        const float f0 = bf2f((ushort)(v[w] & 0xffff)), f1 = bf2f((ushort)(v[w] >> 16));
        s1 += f0 + f1; s2 += f0*f0 + f1*f1;
      }
      *(uintx4*)(xrow_w + (((uint)(part*32 + j*16)) ^ swl)) = v;
    }
  }
  s1 += __shfl_xor(s1, 1); s2 += __shfl_xor(s2, 1);
  s1 += __shfl_xor(s1, 2); s2 += __shfl_xor(s2, 2);
  s1 += __shfl_xor(s1, 4); s2 += __shfl_xor(s2, 4);
  if (part == 0){
    const float mean = s1 * (1.f/128.f);
    const float var  = s2 * (1.f/128.f) - mean*mean;
    rstat[lm] = make_float2(mean, rsqrtf(var + 1e-5f));
  }
  __syncthreads();                     // xb + rstat + params ready -- only barrier

  // ---- MFMA K-loop: wave = (rowgrp rg, colgrp wn); 16 rows x 64 cols, acc[4] ----
  const int l15 = lane & 15, l4h = lane >> 4;
  const int rg = wv >> 1, wn = wv & 1;
  const int row = rg*16 + l15;
  const uint swz = ((uint)(row & 7)) << 4;
  const char* xrow = xb + row*256;
  const float2 st = rstat[row];
  const float mrow = st.x, rrow = st.y;

  floatx4 acc[4];
  #pragma unroll
  for (int nr = 0; nr < 4; ++nr){ floatx4 z4 = {0.f,0.f,0.f,0.f}; acc[nr] = z4; }

  const short8* w8 = (const short8*)wimg;
  const int nbase = wn*4;              // global nr = nbase + nrl

  auto afrag = [&](int sp)->short8 {
    const int q = sp >> 1, ks = sp & 1;
    if (q < 8){
      const int f0 = q*16 + ks*8 + l4h*2;
      const uint xx = *(const uint*)(xrow + (((uint)(f0*2)) ^ swz));
      const float x0 = bf2f((ushort)(xx & 0xffff)), x1 = bf2f((ushort)(xx >> 16));
      const float2 ls = *(const float2*)(lnS + f0);
      const float2 lb = *(const float2*)(lnB + f0);
      const float z0 = (x0 - mrow)*rrow*ls.x + lb.x;
      const float z1 = (x1 - mrow)*rrow*ls.y + lb.y;
      // exp(-(0.75 d)^2) = exp2(d*d * -0.5625*log2(e)), d = z - gc
      const float C = -0.81152344f;
      float e0[4], e1[4];
      #pragma unroll
      for (int g = 0; g < 4; ++g){
        const float gc = -2.f + (4.f/3.f)*(float)g;
        const float d0 = z0 - gc, d1 = z1 - gc;
        e0[g] = exp2f(d0*d0*C);
        e1[g] = exp2f(d1*d1*C);
      }
      uintx4 pw;
      pw.x = pkbf(e0[0], e0[1]); pw.y = pkbf(e0[2], e0[3]);
      pw.z = pkbf(e1[0], e1[1]); pw.w = pkbf(e1[2], e1[3]);
      return __builtin_bit_cast(short8, pw);
    } else {
      const int f0 = (q - 8)*64 + ks*32 + l4h*8;
      const uintx4 xx = *(const uintx4*)(xrow + (((uint)(f0*2)) ^ swz));
      uintx4 pw;
      #pragma unroll
      for (int w = 0; w < 4; ++w){
        const float x0 = bf2f((ushort)(xx[w] & 0xffff)), x1 = bf2f((ushort)(xx[w] >> 16));
        pw[w] = pkbf(fsilu(x0), fsilu(x1));
      }
      return __builtin_bit_cast(short8, pw);
    }
  };

  short8 b0[4], b1[4];
  #pragma unroll
  for (int nrl = 0; nrl < 4; ++nrl)
    b0[nrl] = w8[(size_t)((nbase + nrl)*2)*64 + lane];   // sp=0

  #pragma unroll
  for (int sp = 0; sp < 20; sp += 2){
    {   // prefetch sp+1 into b1
      const int q1 = (sp + 1) >> 1, ks1 = (sp + 1) & 1;
      #pragma unroll
      for (int nrl = 0; nrl < 4; ++nrl)
        b1[nrl] = w8[(size_t)(q1*16 + (nbase + nrl)*2 + ks1)*64 + lane];
    }
    {
      const short8 af = afrag(sp);
      #pragma unroll
      for (int nrl = 0; nrl < 4; ++nrl)
        acc[nrl] = __builtin_amdgcn_mfma_f32_16x16x32_bf16(af, b0[nrl], acc[nrl], 0, 0, 0);
    }
    if (sp + 2 < 20){   // prefetch sp+2 into b0
      const int q2 = (sp + 2) >> 1, ks2 = (sp + 2) & 1;
      #pragma unroll
      for (int nrl = 0; nrl < 4; ++nrl)
        b0[nrl] = w8[(size_t)(q2*16 + (nbase + nrl)*2 + ks2)*64 + lane];
    }
    {
      const short8 af = afrag(sp + 1);
      #pragma unroll
      for (int nrl = 0; nrl < 4; ++nrl)
        acc[nrl] = __builtin_amdgcn_mfma_f32_16x16x32_bf16(af, b1[nrl], acc[nrl], 0, 0, 0);
    }
  }

  // ---- epilogue: h' = dinv * (acc + bias), bf16 store ----
  const int rbase = node0 + rg*16 + l4h*4;
  float dvv[4];
  #pragma unroll
  for (int j = 0; j < 4; ++j) dvv[j] = dinv[rbase + j];
  #pragma unroll
  for (int nrl = 0; nrl < 4; ++nrl){
    const int cf = wn*64 + nrl*16 + l15;
    const float sv = sbias[cf];
    #pragma unroll
    for (int j = 0; j < 4; ++j)
      hprime[(size_t)(rbase + j)*FEAT + cf] = f2bf(dvv[j]*(acc[nrl][j] + sv));
  }
}

// ---------------- CSR aggregation + silu + bias (one wave per dst node, register accum) ----------------
__global__ __launch_bounds__(256) void k_aggD(
    const ushort* __restrict__ hprime, const int* __restrict__ rp,
    const int* __restrict__ col, const float* __restrict__ dinv,
    const float* __restrict__ gb, ushort* __restrict__ xout)
{
  const int wv = threadIdx.x >> 6, lane = threadIdx.x & 63;
  const int d = blockIdx.x*4 + wv;
  if (d >= NN) return;
  const uint* h2 = (const uint*)hprime;
  const uint v = h2[(size_t)d*64 + lane];
  float a0 = bf2f((ushort)(v & 0xffff)), a1 = bf2f((ushort)(v >> 16));
  const int j0 = rp[d], j1 = rp[d+1];
  int j = j0;
  for (; j + 7 < j1; j += 8){
    uint w[8];
    #pragma unroll
    for (int u = 0; u < 8; ++u) w[u] = h2[(size_t)col[j+u]*64 + lane];
    #pragma unroll
    for (int u = 0; u < 8; ++u){
      a0 += bf2f((ushort)(w[u] & 0xffff));
      a1 += bf2f((ushort)(w[u] >> 16));
    }
  }
  for (; j + 3 < j1; j += 4){
    uint w[4];
    #pragma unroll
    for (int u = 0; u < 4; ++u) w[u] = h2[(size_t)col[j+u]*64 + lane];
    #pragma unroll
    for (int u = 0; u < 4; ++u){
      a0 += bf2f((ushort)(w[u] & 0xffff));
      a1 += bf2f((ushort)(w[u] >> 16));
    }
  }
  for (; j < j1; ++j){
    const uint w = h2[(size_t)col[j]*64 + lane];
    a0 += bf2f((ushort)(w & 0xffff)); a1 += bf2f((ushort)(w >> 16));
  }
  const float dv = dinv[d];
  const float2 b2 = *(const float2*)(gb + 2*lane);
  a0 = fsilu(dv*a0 + b2.x);
  a1 = fsilu(dv*a1 + b2.y);
  ((uint*)xout)[(size_t)d*64 + lane] = (uint)f2bf(a0) | ((uint)f2bf(a1) << 16);
}

// ---------------- pooling (sorted batch) ----------------
__global__ __launch_bounds__(128) void k_pool(const ushort* __restrict__ x,
                                              const int* __restrict__ batch,
                                              float* __restrict__ pooled,
                                              float* __restrict__ cnt, int n){
  const int f = threadIdx.x;
  const int start = blockIdx.x * 64;
  const int end   = min(start + 64, n);
  if (start >= end) return;
  int cur = batch[start];
  float acc = 0.f, c = 0.f;
  for (int i = start; i < end; ++i){
    const int b = batch[i];
    if (b != cur){
      atomicAdd(&pooled[(size_t)cur*FEAT + f], acc);
      if (f == 0) atomicAdd(&cnt[cur], c);
      cur = b; acc = 0.f; c = 0.f;
    }
    acc += bf2f(x[(size_t)i*FEAT + f]);
    c += 1.f;
  }
  atomicAdd(&pooled[(size_t)cur*FEAT + f], acc);
  if (f == 0) atomicAdd(&cnt[cur], c);
}

__global__ __launch_bounds__(128) void k_pool_div(float* __restrict__ pooled,
                                                  const float* __restrict__ cnt){
  const int g = blockIdx.x, f = threadIdx.x;
  pooled[(size_t)g*FEAT + f] /= fmaxf(cnt[g], 1.f);
}

// ---------------- readout FastKAN (128 -> 10) + log_softmax ----------------
__global__ __launch_bounds__(128) void k_readout(const float* __restrict__ pooled,
    const float* __restrict__ ln_s, const float* __restrict__ ln_b,
    const float* __restrict__ sW, const float* __restrict__ sb,
    const float* __restrict__ bW, const float* __restrict__ bb,
    float* __restrict__ out){
  __shared__ float cb[KSPL + FEAT];
  __shared__ float wred[2][2];
  __shared__ float outv[NCLS];
  const int tid = threadIdx.x, lane = tid & 63, wave = tid >> 6;
  const int g = blockIdx.x;

  const float xvv = pooled[(size_t)g*FEAT + tid];
  float s1 = xvv, s2 = xvv*xvv;
  #pragma unroll
  for (int off = 32; off; off >>= 1){ s1 += __shfl_down(s1, off); s2 += __shfl_down(s2, off); }
  if (lane == 0){ wred[wave][0] = s1; wred[wave][1] = s2; }
  __syncthreads();
  const float m   = (wred[0][0] + wred[1][0]) * (1.f/FEAT);
  const float var = (wred[0][1] + wred[1][1]) * (1.f/FEAT) - m*m;
  const float rs  = rsqrtf(var + 1e-5f);
  const float z   = (xvv - m) * rs * ln_s[tid] + ln_b[tid];
  #pragma unroll
  for (int gg = 0; gg < GQ; ++gg){
    const float t = (z - (-2.f + (4.f/3.f)*(float)gg)) * 0.75f;
    cb[tid*GQ + gg] = __expf(-t*t);
  }
  cb[KSPL + tid] = fsilu(xvv);
  __syncthreads();

  if (tid < NCLS){
    const float* wr = sW + (size_t)tid*KSPL;
    const float* br = bW + (size_t)tid*FEAT;
    float acc = sb[tid] + bb[tid];
    for (int k = 0; k < KSPL; ++k) acc += cb[k] * wr[k];
    for (int k = 0; k < FEAT; ++k) acc += cb[KSPL + k] * br[k];
    outv[tid] = acc;
  }
  __syncthreads();
  if (tid == 0){
    float mx = -1e30f;
    for (int o = 0; o < NCLS; ++o) mx = fmaxf(mx, outv[o]);
    float se = 0.f;
    for (int o = 0; o < NCLS; ++o) se += __expf(outv[o] - mx);
    const float lse = mx + logf(se);
    for (int o = 0; o < NCLS; ++o) out[(size_t)g*NCLS + o] = outv[o] - lse;
  }
}

extern "C" void kernel_launch(void* const* d_in, const int* in_sizes, int n_in,
                              void* d_out, int out_size, void* d_ws, size_t ws_size,
                              hipStream_t stream) {
  const float* x     = (const float*)d_in[0];
  const int*   edge  = (const int*)d_in[1];
  const int*   batch = (const int*)d_in[2];
  const float* ln_s  = (const float*)d_in[3];
  const float* ln_b  = (const float*)d_in[4];
  const float* sW    = (const float*)d_in[5];
  const float* sb    = (const float*)d_in[6];
  const float* bW    = (const float*)d_in[7];
  const float* bb    = (const float*)d_in[8];
  const float* gcn_b = (const float*)d_in[9];
  const float* ro_ln_s = (const float*)d_in[10];
  const float* ro_ln_b = (const float*)d_in[11];
  const float* ro_sW   = (const float*)d_in[12];
  const float* ro_sb   = (const float*)d_in[13];
  const float* ro_bW   = (const float*)d_in[14];
  const float* ro_bb   = (const float*)d_in[15];
  float* out = (float*)d_out;

  const int* src = edge;
  const int* dst = edge + NE;

  char* W = (char*)d_ws;
  size_t off = 0;
  auto alloc = [&](size_t bytes){ size_t r = off; off += (bytes + 1023) & ~((size_t)1023); return r; };
  float*  dinv   = (float*) (W + alloc((size_t)NN*4));
  ushort* wimg   = (ushort*)(W + alloc((size_t)NL*WSTRIDE*2));
  int*    hist   = (int*)   (W + alloc((size_t)NN*4));
  int*    rp     = (int*)   (W + alloc((size_t)(NN+1)*4));
  int*    tsum   = (int*)   (W + alloc((size_t)NT*4));
  int*    toff   = (int*)   (W + alloc((size_t)NT*4));
  uint*   priv   = (uint*)  (W + alloc((size_t)NE*4));
  int*    seg    = (int*)   (W + alloc((size_t)NCHUNK*(NB+1)*4));
  int*    col    = (int*)   (W + alloc((size_t)NE*4));
  ushort* hprime = (ushort*)(W + alloc((size_t)NN*FEAT*2));
  ushort* xcur   = (ushort*)(W + alloc((size_t)NN*FEAT*2));
  float*  pooled = (float*) (W + alloc((size_t)(NGR*FEAT + NGR)*4));
  float*  cnt    = pooled + NGR*FEAT;

  // degree norm + CSR build (layer-invariant)
  k_zero_i<<<(NN+255)/256, 256, 0, stream>>>(hist, NN);
  k_zero_f<<<(NGR*FEAT+NGR+255)/256, 256, 0, stream>>>(pooled, NGR*FEAT + NGR);
  k_hist<<<(NE+255)/256, 256, 0, stream>>>(dst, hist, NE);
  k_scan_a<<<NT, 256, 0, stream>>>(hist, tsum);
  k_scan_b<<<1, 128, 0, stream>>>(tsum, toff, rp + NN);
  k_scan_c<<<NT, 256, 0, stream>>>(hist, toff, rp, dinv);
  k_binA<<<NCHUNK, 256, 0, stream>>>(src, dst, priv, seg);
  k_gathE2<<<NB, 256, 0, stream>>>(priv, seg, rp, col);
  k_wprep<<<(NL*WSTRIDE + 255)/256, 256, 0, stream>>>(sW, bW, wimg);

  const int fkan_grid = NN / BM;
  for (int l = 0; l < NL; ++l){
    const ushort* wl = wimg + (size_t)l*WSTRIDE;
    if (l == 0)
      k_fkan<float><<<fkan_grid, 256, 0, stream>>>(x, wl,
          ln_s + l*FEAT, ln_b + l*FEAT, sb + l*FEAT, bb + l*FEAT, dinv, hprime);
    else
      k_fkan<ushort><<<fkan_grid, 256, 0, stream>>>(xcur, wl,
          ln_s + l*FEAT, ln_b + l*FEAT, sb + l*FEAT, bb + l*FEAT, dinv, hprime);
    k_aggD<<<(NN+3)/4, 256, 0, stream>>>(hprime, rp, col, dinv, gcn_b + l*FEAT, xcur);
  }

  k_pool<<<(NN+63)/64, 128, 0, stream>>>(xcur, batch, pooled, cnt, NN);
  k_pool_div<<<NGR, 128, 0, stream>>>(pooled, cnt);
  k_readout<<<NGR, 128, 0, stream>>>(pooled, ro_ln_s, ro_ln_b,
                                     ro_sW, ro_sb, ro_bW, ro_bb, out);
}

// Round 15
// 483.324 us; speedup vs baseline: 1.0958x; 1.0958x over previous
//
#include <hip/hip_runtime.h>
#include <math.h>

#define NN     100000
#define NE     1600000
#define FEAT   128
#define GQ     4
#define NL     3
#define NGR    64
#define NCLS   10
#define KSPL   512
#define NKS    10            /* K-steps of 64 (640 total) */
#define BM     32            /* nodes per block (128 threads, 2 waves) */
#define NB     1563          /* dst buckets of 64 nodes: ceil(NN/64) */
#define NCHUNK 256
#define CHUNK  6250          /* NE / NCHUNK */
#define TILE   1024
#define NT     ((NN + TILE - 1) / TILE)   /* 98 scan tiles */
#define WSTRIDE (NKS*8*2*512)             /* 81920 ushorts per layer */

typedef __attribute__((ext_vector_type(8))) short short8;
typedef __attribute__((ext_vector_type(4))) float floatx4;
typedef __attribute__((ext_vector_type(4))) uint uintx4;

__device__ __forceinline__ float fsilu(float x){ return x / (1.f + __expf(-x)); }
__device__ __forceinline__ ushort f2bf(float f){
  uint u = __builtin_bit_cast(uint, f);
  return (ushort)((u + 0x7FFFu + ((u >> 16) & 1u)) >> 16);
}
__device__ __forceinline__ float bf2f(ushort h){ return __builtin_bit_cast(float, ((uint)h) << 16); }
__device__ __forceinline__ uint bu(float f){ return __builtin_bit_cast(uint, f); }
__device__ __forceinline__ uint pkbf(float lo, float hi){
  return __builtin_amdgcn_perm(bu(hi), bu(lo), 0x07060302u);  // truncating bf16x2 pack
}

// ---------------- small utility kernels ----------------
__global__ __launch_bounds__(256) void k_zero_i(int* __restrict__ p, int n){
  int i = blockIdx.x*256 + threadIdx.x; if (i < n) p[i] = 0;
}
__global__ __launch_bounds__(256) void k_zero_f(float* __restrict__ p, int n){
  int i = blockIdx.x*256 + threadIdx.x; if (i < n) p[i] = 0.f;
}
__global__ __launch_bounds__(256) void k_hist(const int* __restrict__ dst, int* __restrict__ hist, int ne){
  int e = blockIdx.x*256 + threadIdx.x; if (e < ne) atomicAdd(&hist[dst[e]], 1);
}

// ---- hierarchical exclusive scan over hist[NN] -> rp, dinv ----
__global__ __launch_bounds__(256) void k_scan_a(const int* __restrict__ hist, int* __restrict__ tsum){
  __shared__ int red[4];
  const int base = blockIdx.x * TILE;
  int s = 0;
  #pragma unroll
  for (int j = 0; j < 4; ++j){
    int idx = base + threadIdx.x + j*256;
    if (idx < NN) s += hist[idx];
  }
  #pragma unroll
  for (int off = 32; off; off >>= 1) s += __shfl_down(s, off);
  if ((threadIdx.x & 63) == 0) red[threadIdx.x >> 6] = s;
  __syncthreads();
  if (threadIdx.x == 0) tsum[blockIdx.x] = red[0] + red[1] + red[2] + red[3];
}

__global__ __launch_bounds__(128) void k_scan_b(const int* __restrict__ tsum,
                                                int* __restrict__ toff, int* __restrict__ rpN){
  __shared__ int lds[128];
  const int tid = threadIdx.x;
  int v = (tid < NT) ? tsum[tid] : 0;
  lds[tid] = v; __syncthreads();
  for (int off = 1; off < 128; off <<= 1){
    int u = (tid >= off) ? lds[tid - off] : 0;
    __syncthreads();
    lds[tid] += u;
    __syncthreads();
  }
  if (tid < NT) toff[tid] = lds[tid] - v;
  if (tid == NT - 1) *rpN = lds[tid];
}

__global__ __launch_bounds__(256) void k_scan_c(const int* __restrict__ hist,
                                                const int* __restrict__ toff,
                                                int* __restrict__ rp,
                                                float* __restrict__ dinv){
  __shared__ int lds[256];
  const int tid = threadIdx.x;
  const int base = blockIdx.x * TILE + tid*4;
  int h[4]; int s = 0;
  #pragma unroll
  for (int j = 0; j < 4; ++j){ int idx = base + j; h[j] = (idx < NN) ? hist[idx] : 0; s += h[j]; }
  lds[tid] = s; __syncthreads();
  for (int off = 1; off < 256; off <<= 1){
    int u = (tid >= off) ? lds[tid - off] : 0;
    __syncthreads();
    lds[tid] += u;
    __syncthreads();
  }
  int run = toff[blockIdx.x] + lds[tid] - s;
  #pragma unroll
  for (int j = 0; j < 4; ++j){
    int idx = base + j;
    if (idx < NN){
      rp[idx] = run; run += h[j];
      dinv[idx] = rsqrtf((float)h[j] + 1.f);
    }
  }
}

// ---- chunk-private binning: each block bins its 6250 edges by dst>>6 into its own region ----
// edge packed as (src<<6) | (dst&63)
__global__ __launch_bounds__(256) void k_binA(const int* __restrict__ src, const int* __restrict__ dst,
                                              uint* __restrict__ priv, int* __restrict__ seg){
  __shared__ int hist[NB];
  __shared__ int cur[NB];
  __shared__ int scanbuf[256];
  const int c = blockIdx.x, tid = threadIdx.x;
  const size_t e0 = (size_t)c * CHUNK;
  for (int i = tid; i < NB; i += 256) hist[i] = 0;
  __syncthreads();
  for (int i = tid; i < CHUNK; i += 256) atomicAdd(&hist[dst[e0+i] >> 6], 1);
  __syncthreads();
  int loc[7]; int s = 0;
  const int base = tid * 7;
  #pragma unroll
  for (int j = 0; j < 7; ++j){ int idx = base+j; int v = (idx < NB) ? hist[idx] : 0; loc[j] = s; s += v; }
  scanbuf[tid] = s;
  __syncthreads();
  for (int off = 1; off < 256; off <<= 1){
    int u = (tid >= off) ? scanbuf[tid-off] : 0;
    __syncthreads();
    scanbuf[tid] += u;
    __syncthreads();
  }
  const int run = scanbuf[tid] - s;
  #pragma unroll
  for (int j = 0; j < 7; ++j){
    int idx = base+j;
    if (idx < NB){ int st = run + loc[j]; seg[c*(NB+1)+idx] = st; cur[idx] = st; }
  }
  if (tid == 0) seg[c*(NB+1)+NB] = CHUNK;
  __syncthreads();
  for (int i = tid; i < CHUNK; i += 256){
    const uint ss = (uint)src[e0+i], dd = (uint)dst[e0+i];
    const int p = atomicAdd(&cur[dd >> 6], 1);
    priv[(size_t)c*CHUNK + p] = (ss << 6) | (dd & 63u);
  }
}

// per bucket: scatter chunk-private edges into dst-node-sorted col via rp cursors
__global__ __launch_bounds__(256) void k_gathE2(const uint* __restrict__ priv, const int* __restrict__ seg,
                                                const int* __restrict__ rp, int* __restrict__ col){
  __shared__ int cur[64];
  const int b = blockIdx.x, tid = threadIdx.x;
  const int n0 = b * 64;
  if (tid < 64){
    const int idx = n0 + tid;
    cur[tid] = rp[(idx < NN) ? idx : NN];
  }
  __syncthreads();
  const int c = tid;
  const int s0 = seg[c*(NB+1) + b], s1 = seg[c*(NB+1) + b + 1];
  const size_t pbase = (size_t)c*CHUNK;
  for (int i = s0; i < s1; ++i){
    const uint e = priv[pbase + i];
    const int p = atomicAdd(&cur[e & 63u], 1);
    col[p] = (int)(e >> 6);
  }
}

// weights -> bf16 in per-lane MFMA fragment layout:
// frag id = q*16 + nr*2 + ks ; wimg[frag][lane*8+j] = W[col][k]
//   col = nr*16+(lane&15), k = q*64+ks*32+(lane>>4)*8+j
__global__ __launch_bounds__(256) void k_wprep(const float* __restrict__ sW, const float* __restrict__ bW,
                                               ushort* __restrict__ wimg){
  int idx = blockIdx.x*256 + threadIdx.x;
  if (idx >= NL*WSTRIDE) return;
  const int j    = idx & 7;
  const int lane = (idx >> 3) & 63;
  const int ks   = (idx >> 9) & 1;
  const int nr   = (idx >> 10) & 7;
  const int qq   = (idx >> 13) % NKS;
  const int l    = idx / (NKS << 13);
  const int colc = nr*16 + (lane & 15);
  const int kg   = qq*64 + ks*32 + (lane >> 4)*8 + j;
  const float v  = (kg < KSPL) ? sW[((size_t)l*FEAT + colc)*KSPL + kg]
                               : bW[((size_t)l*FEAT + colc)*FEAT + (kg - KSPL)];
  wimg[idx] = f2bf(v);
}

// ---------------- FKAN transform: single x-tile in LDS, inline LN/silu, 2-deep B prefetch ----------------
template <typename TIn>
__global__ __launch_bounds__(128) void k_fkan(
    const TIn* __restrict__ xin,            // [NN][128] fp32 or bf16(ushort)
    const ushort* __restrict__ wimg,        // this layer's fragment image (L2-resident)
    const float* __restrict__ ln_s, const float* __restrict__ ln_b,
    const float* __restrict__ sb, const float* __restrict__ bb,
    const float* __restrict__ dinv,
    ushort* __restrict__ hprime)
{
  __shared__ char xb[BM*256];        // x bf16 [32][128], xor-swizzled rows  (8 KB)
  __shared__ float lnS[128], lnB[128], sbias[128];

  const int tid  = threadIdx.x;
  const int lane = tid & 63, wv = tid >> 6;
  const int node0 = blockIdx.x * BM;   // NN % BM == 0: no guards anywhere

  lnS[tid] = ln_s[tid]; lnB[tid] = ln_b[tid]; sbias[tid] = sb[tid] + bb[tid];

  // ---- LN stats phase: 4 threads per node, 32 feats each; stage bf16 x in LDS ----
  const int lm = tid >> 2, part = tid & 3;
  const int node = node0 + lm;
  const uint swl = ((uint)(lm & 7)) << 4;
  char* xrow_w = xb + lm*256;
  float s1 = 0.f, s2 = 0.f;
  if constexpr (sizeof(TIn) == 4){
    const float4* xr = (const float4*)((const float*)xin + (size_t)node*FEAT + part*32);
    #pragma unroll
    for (int j = 0; j < 4; ++j){
      const float4 a = xr[2*j], b = xr[2*j+1];
      s1 += a.x+a.y+a.z+a.w + b.x+b.y+b.z+b.w;
      s2 += a.x*a.x+a.y*a.y+a.z*a.z+a.w*a.w + b.x*b.x+b.y*b.y+b.z*b.z+b.w*b.w;
      uintx4 pk;
      pk.x = pkbf(a.x, a.y); pk.y = pkbf(a.z, a.w);
      pk.z = pkbf(b.x, b.y); pk.w = pkbf(b.z, b.w);
      *(uintx4*)(xrow_w + (((uint)(part*64 + j*16)) ^ swl)) = pk;
    }
  } else {
    const uintx4* xr = (const uintx4*)((const ushort*)xin + (size_t)node*FEAT + part*32);
    #pragma unroll
    for (int j = 0; j < 4; ++j){
      const uintx4 v = xr[j];
      #pragma unroll
      for (int w = 0; w < 4; ++w){
        const float f0 = bf2f((ushort)(v[w] & 0xffff)), f1 = bf2f((ushort)(v[w] >> 16));
        s1 += f0 + f1; s2 += f0*f0 + f1*f1;
      }
      *(uintx4*)(xrow_w + (((uint)(part*64 + j*16)) ^ swl)) = v;
    }
  }
  s1 += __shfl_xor(s1, 1); s2 += __shfl_xor(s2, 1);
  s1 += __shfl_xor(s1, 2); s2 += __shfl_xor(s2, 2);
  const float mean = s1 * (1.f/128.f);
  const float var  = s2 * (1.f/128.f) - mean*mean;
  const float rsv  = rsqrtf(var + 1e-5f);
  __syncthreads();                       // xb + lnS/lnB/sbias ready -- only barrier

  // ---- MFMA K-loop: wave owns rows wv*16..+15, all 128 cols ----
  const int l15 = lane & 15, l4h = lane >> 4;
  const int row = wv*16 + l15;
  const uint swz = ((uint)(row & 7)) << 4;
  const char* xrow = xb + row*256;
  // fetch this row's LN stats from the thread that computed them (lane l15*4)
  const float mrow = __shfl(mean, (lane & 15) << 2);
  const float rrow = __shfl(rsv,  (lane & 15) << 2);

  floatx4 acc[8];
  #pragma unroll
  for (int nr = 0; nr < 8; ++nr){ floatx4 z4 = {0.f,0.f,0.f,0.f}; acc[nr] = z4; }

  const short8* w8 = (const short8*)wimg;

  auto afrag = [&](int sp)->short8 {
    const int q = sp >> 1, ks = sp & 1;
    if (q < 8){
      const int f0 = q*16 + ks*8 + l4h*2;
      const uint xx = *(const uint*)(xrow + (((uint)(f0*2)) ^ swz));
      const float x0 = bf2f((ushort)(xx & 0xffff)), x1 = bf2f((ushort)(xx >> 16));
      const float2 ls = *(const float2*)(lnS + f0);
      const float2 lb = *(const float2*)(lnB + f0);
      const float z0 = (x0 - mrow)*rrow*ls.x + lb.x;
      const float z1 = (x1 - mrow)*rrow*ls.y + lb.y;
      // exp(-(0.75 d)^2) = exp2(d*d * -0.5625*log2(e))
      const float C = -0.81151599f;
      float e0[4], e1[4];
      #pragma unroll
      for (int g = 0; g < 4; ++g){
        const float gc = -2.f + (4.f/3.f)*(float)g;
        const float d0 = z0 - gc, d1 = z1 - gc;
        e0[g] = exp2f(d0*d0*C);
        e1[g] = exp2f(d1*d1*C);
      }
      uintx4 pw;
      pw.x = pkbf(e0[0], e0[1]); pw.y = pkbf(e0[2], e0[3]);
      pw.z = pkbf(e1[0], e1[1]); pw.w = pkbf(e1[2], e1[3]);
      return __builtin_bit_cast(short8, pw);
    } else {
      const int f0 = (q - 8)*64 + ks*32 + l4h*8;
      const uintx4 xx = *(const uintx4*)(xrow + (((uint)(f0*2)) ^ swz));
      uintx4 pw;
      #pragma unroll
      for (int w = 0; w < 4; ++w){
        const float x0 = bf2f((ushort)(xx[w] & 0xffff)), x1 = bf2f((ushort)(xx[w] >> 16));
        pw[w] = pkbf(fsilu(x0), fsilu(x1));
      }
      return __builtin_bit_cast(short8, pw);
    }
  };

  short8 b0[8], b1[8];
  #pragma unroll
  for (int nr = 0; nr < 8; ++nr) b0[nr] = w8[(size_t)(nr*2)*64 + lane];   // sp=0

  #pragma unroll
  for (int sp = 0; sp < 20; sp += 2){
    {   // prefetch sp+1 into b1
      const int q1 = (sp + 1) >> 1, ks1 = (sp + 1) & 1;
      #pragma unroll
      for (int nr = 0; nr < 8; ++nr) b1[nr] = w8[(size_t)(q1*16 + nr*2 + ks1)*64 + lane];
    }
    {
      const short8 af = afrag(sp);
      #pragma unroll
      for (int nr = 0; nr < 8; ++nr)
        acc[nr] = __builtin_amdgcn_mfma_f32_16x16x32_bf16(af, b0[nr], acc[nr], 0, 0, 0);
    }
    if (sp + 2 < 20){   // prefetch sp+2 into b0
      const int q2 = (sp + 2) >> 1, ks2 = (sp + 2) & 1;
      #pragma unroll
      for (int nr = 0; nr < 8; ++nr) b0[nr] = w8[(size_t)(q2*16 + nr*2 + ks2)*64 + lane];
    }
    {
      const short8 af = afrag(sp + 1);
      #pragma unroll
      for (int nr = 0; nr < 8; ++nr)
        acc[nr] = __builtin_amdgcn_mfma_f32_16x16x32_bf16(af, b1[nr], acc[nr], 0, 0, 0);
    }
  }

  // ---- epilogue: h' = dinv * (acc + bias), bf16 store ----
  const int rbase = node0 + wv*16 + l4h*4;
  float dvv[4];
  #pragma unroll
  for (int j = 0; j < 4; ++j) dvv[j] = dinv[rbase + j];
  #pragma unroll
  for (int nr = 0; nr < 8; ++nr){
    const int cf = nr*16 + l15;
    const float sv = sbias[cf];
    #pragma unroll
    for (int j = 0; j < 4; ++j)
      hprime[(size_t)(rbase + j)*FEAT + cf] = f2bf(dvv[j]*(acc[nr][j] + sv));
  }
}

// ---------------- CSR aggregation: 2 dst per wave (32-lane halves), uint2 row gathers ----------------
__global__ __launch_bounds__(256) void k_aggD(
    const ushort* __restrict__ hprime, const int* __restrict__ rp,
    const int* __restrict__ col, const float* __restrict__ dinv,
    const float* __restrict__ gb, ushort* __restrict__ xout)
{
  const int wv = threadIdx.x >> 6, lane = threadIdx.x & 63;
  const int half = lane >> 5, li = lane & 31;
  const int d = blockIdx.x*8 + wv*2 + half;   // NN = 12500*8 exactly
  const uint2* h2 = (const uint2*)hprime;     // row = 32 uint2 (8B per lane covers 4 feats)

  const uint2 v = h2[(size_t)d*32 + li];
  float a0 = bf2f((ushort)(v.x & 0xffff)), a1 = bf2f((ushort)(v.x >> 16));
  float a2 = bf2f((ushort)(v.y & 0xffff)), a3 = bf2f((ushort)(v.y >> 16));

  const int j0 = rp[d], j1 = rp[d+1];
  int j = j0;
  for (; j + 7 < j1; j += 8){
    uint2 w[8];
    #pragma unroll
    for (int u = 0; u < 8; ++u) w[u] = h2[(size_t)col[j+u]*32 + li];
    #pragma unroll
    for (int u = 0; u < 8; ++u){
      a0 += bf2f((ushort)(w[u].x & 0xffff)); a1 += bf2f((ushort)(w[u].x >> 16));
      a2 += bf2f((ushort)(w[u].y & 0xffff)); a3 += bf2f((ushort)(w[u].y >> 16));
    }
  }
  for (; j + 3 < j1; j += 4){
    uint2 w[4];
    #pragma unroll
    for (int u = 0; u < 4; ++u) w[u] = h2[(size_t)col[j+u]*32 + li];
    #pragma unroll
    for (int u = 0; u < 4; ++u){
      a0 += bf2f((ushort)(w[u].x & 0xffff)); a1 += bf2f((ushort)(w[u].x >> 16));
      a2 += bf2f((ushort)(w[u].y & 0xffff)); a3 += bf2f((ushort)(w[u].y >> 16));
    }
  }
  for (; j < j1; ++j){
    const uint2 w = h2[(size_t)col[j]*32 + li];
    a0 += bf2f((ushort)(w.x & 0xffff)); a1 += bf2f((ushort)(w.x >> 16));
    a2 += bf2f((ushort)(w.y & 0xffff)); a3 += bf2f((ushort)(w.y >> 16));
  }

  const float dv = dinv[d];
  const float4 b4 = *(const float4*)(gb + li*4);
  a0 = fsilu(dv*a0 + b4.x);
  a1 = fsilu(dv*a1 + b4.y);
  a2 = fsilu(dv*a2 + b4.z);
  a3 = fsilu(dv*a3 + b4.w);
  uint2 o;
  o.x = (uint)f2bf(a0) | ((uint)f2bf(a1) << 16);
  o.y = (uint)f2bf(a2) | ((uint)f2bf(a3) << 16);
  ((uint2*)xout)[(size_t)d*32 + li] = o;
}

// ---------------- pooling (sorted batch) ----------------
__global__ __launch_bounds__(128) void k_pool(const ushort* __restrict__ x,
                                              const int* __restrict__ batch,
                                              float* __restrict__ pooled,
                                              float* __restrict__ cnt, int n){
  const int f = threadIdx.x;
  const int start = blockIdx.x * 64;
  const int end   = min(start + 64, n);
  if (start >= end) return;
  int cur = batch[start];
  float acc = 0.f, c = 0.f;
  for (int i = start; i < end; ++i){
    const int b = batch[i];
    if (b != cur){
      atomicAdd(&pooled[(size_t)cur*FEAT + f], acc);
      if (f == 0) atomicAdd(&cnt[cur], c);
      cur = b; acc = 0.f; c = 0.f;
    }
    acc += bf2f(x[(size_t)i*FEAT + f]);
    c += 1.f;
  }
  atomicAdd(&pooled[(size_t)cur*FEAT + f], acc);
  if (f == 0) atomicAdd(&cnt[cur], c);
}

__global__ __launch_bounds__(128) void k_pool_div(float* __restrict__ pooled,
                                                  const float* __restrict__ cnt){
  const int g = blockIdx.x, f = threadIdx.x;
  pooled[(size_t)g*FEAT + f] /= fmaxf(cnt[g], 1.f);
}

// ---------------- readout FastKAN (128 -> 10) + log_softmax ----------------
__global__ __launch_bounds__(128) void k_readout(const float* __restrict__ pooled,
    const float* __restrict__ ln_s, const float* __restrict__ ln_b,
    const float* __restrict__ sW, const float* __restrict__ sb,
    const float* __restrict__ bW, const float* __restrict__ bb,
    float* __restrict__ out){
  __shared__ float cb[KSPL + FEAT];
  __shared__ float wred[2][2];
  __shared__ float outv[NCLS];
  const int tid = threadIdx.x, lane = tid & 63, wave = tid >> 6;
  const int g = blockIdx.x;

  const float xvv = pooled[(size_t)g*FEAT + tid];
  float s1 = xvv, s2 = xvv*xvv;
  #pragma unroll
  for (int off = 32; off; off >>= 1){ s1 += __shfl_down(s1, off); s2 += __shfl_down(s2, off); }
  if (lane == 0){ wred[wave][0] = s1; wred[wave][1] = s2; }
  __syncthreads();
  const float m   = (wred[0][0] + wred[1][0]) * (1.f/FEAT);
  const float var = (wred[0][1] + wred[1][1]) * (1.f/FEAT) - m*m;
  const float rs  = rsqrtf(var + 1e-5f);
  const float z   = (xvv - m) * rs * ln_s[tid] + ln_b[tid];
  #pragma unroll
  for (int gg = 0; gg < GQ; ++gg){
    const float t = (z - (-2.f + (4.f/3.f)*(float)gg)) * 0.75f;
    cb[tid*GQ + gg] = __expf(-t*t);
  }
  cb[KSPL + tid] = fsilu(xvv);
  __syncthreads();

  if (tid < NCLS){
    const float* wr = sW + (size_t)tid*KSPL;
    const float* br = bW + (size_t)tid*FEAT;
    float acc = sb[tid] + bb[tid];
    for (int k = 0; k < KSPL; ++k) acc += cb[k] * wr[k];
    for (int k = 0; k < FEAT; ++k) acc += cb[KSPL + k] * br[k];
    outv[tid] = acc;
  }
  __syncthreads();
  if (tid == 0){
    float mx = -1e30f;
    for (int o = 0; o < NCLS; ++o) mx = fmaxf(mx, outv[o]);
    float se = 0.f;
    for (int o = 0; o < NCLS; ++o) se += __expf(outv[o] - mx);
    const float lse = mx + logf(se);
    for (int o = 0; o < NCLS; ++o) out[(size_t)g*NCLS + o] = outv[o] - lse;
  }
}

extern "C" void kernel_launch(void* const* d_in, const int* in_sizes, int n_in,
                              void* d_out, int out_size, void* d_ws, size_t ws_size,
                              hipStream_t stream) {
  const float* x     = (const float*)d_in[0];
  const int*   edge  = (const int*)d_in[1];
  const int*   batch = (const int*)d_in[2];
  const float* ln_s  = (const float*)d_in[3];
  const float* ln_b  = (const float*)d_in[4];
  const float* sW    = (const float*)d_in[5];
  const float* sb    = (const float*)d_in[6];
  const float* bW    = (const float*)d_in[7];
  const float* bb    = (const float*)d_in[8];
  const float* gcn_b = (const float*)d_in[9];
  const float* ro_ln_s = (const float*)d_in[10];
  const float* ro_ln_b = (const float*)d_in[11];
  const float* ro_sW   = (const float*)d_in[12];
  const float* ro_sb   = (const float*)d_in[13];
  const float* ro_bW   = (const float*)d_in[14];
  const float* ro_bb   = (const float*)d_in[15];
  float* out = (float*)d_out;

  const int* src = edge;
  const int* dst = edge + NE;

  char* W = (char*)d_ws;
  size_t off = 0;
  auto alloc = [&](size_t bytes){ size_t r = off; off += (bytes + 1023) & ~((size_t)1023); return r; };
  float*  dinv   = (float*) (W + alloc((size_t)NN*4));
  ushort* wimg   = (ushort*)(W + alloc((size_t)NL*WSTRIDE*2));
  int*    hist   = (int*)   (W + alloc((size_t)NN*4));
  int*    rp     = (int*)   (W + alloc((size_t)(NN+1)*4));
  int*    tsum   = (int*)   (W + alloc((size_t)NT*4));
  int*    toff   = (int*)   (W + alloc((size_t)NT*4));
  uint*   priv   = (uint*)  (W + alloc((size_t)NE*4));
  int*    seg    = (int*)   (W + alloc((size_t)NCHUNK*(NB+1)*4));
  int*    col    = (int*)   (W + alloc((size_t)NE*4));
  ushort* hprime = (ushort*)(W + alloc((size_t)NN*FEAT*2));
  ushort* xcur   = (ushort*)(W + alloc((size_t)NN*FEAT*2));
  float*  pooled = (float*) (W + alloc((size_t)(NGR*FEAT + NGR)*4));
  float*  cnt    = pooled + NGR*FEAT;

  // degree norm + CSR build (layer-invariant)
  k_zero_i<<<(NN+255)/256, 256, 0, stream>>>(hist, NN);
  k_zero_f<<<(NGR*FEAT+NGR+255)/256, 256, 0, stream>>>(pooled, NGR*FEAT + NGR);
  k_hist<<<(NE+255)/256, 256, 0, stream>>>(dst, hist, NE);
  k_scan_a<<<NT, 256, 0, stream>>>(hist, tsum);
  k_scan_b<<<1, 128, 0, stream>>>(tsum, toff, rp + NN);
  k_scan_c<<<NT, 256, 0, stream>>>(hist, toff, rp, dinv);
  k_binA<<<NCHUNK, 256, 0, stream>>>(src, dst, priv, seg);
  k_gathE2<<<NB, 256, 0, stream>>>(priv, seg, rp, col);
  k_wprep<<<(NL*WSTRIDE + 255)/256, 256, 0, stream>>>(sW, bW, wimg);

  const int fkan_grid = NN / BM;
  for (int l = 0; l < NL; ++l){
    const ushort* wl = wimg + (size_t)l*WSTRIDE;
    if (l == 0)
      k_fkan<float><<<fkan_grid, 128, 0, stream>>>(x, wl,
          ln_s + l*FEAT, ln_b + l*FEAT, sb + l*FEAT, bb + l*FEAT, dinv, hprime);
    else
      k_fkan<ushort><<<fkan_grid, 128, 0, stream>>>(xcur, wl,
          ln_s + l*FEAT, ln_b + l*FEAT, sb + l*FEAT, bb + l*FEAT, dinv, hprime);
    k_aggD<<<NN/8, 256, 0, stream>>>(hprime, rp, col, dinv, gcn_b + l*FEAT, xcur);
  }

  k_pool<<<(NN+63)/64, 128, 0, stream>>>(xcur, batch, pooled, cnt, NN);
  k_pool_div<<<NGR, 128, 0, stream>>>(pooled, cnt);
  k_readout<<<NGR, 128, 0, stream>>>(pooled, ro_ln_s, ro_ln_b,
                                     ro_sW, ro_sb, ro_bW, ro_bb, out);
}

// Round 16
// 478.447 us; speedup vs baseline: 1.1070x; 1.0102x over previous
//
#include <hip/hip_runtime.h>
#include <math.h>

#define NN     100000
#define NE     1600000
#define FEAT   128
#define GQ     4
#define NL     3
#define NGR    64
#define NCLS   10
#define KSPL   512
#define NKS    10            /* K-steps of 64 (640 total) */
#define BM     32            /* nodes per block (128 threads, 2 waves) */
#define NB     1563          /* dst buckets of 64 nodes: ceil(NN/64) */
#define NCHUNK 256
#define CHUNK  6250          /* NE / NCHUNK */
#define TILE   1024
#define NT     ((NN + TILE - 1) / TILE)   /* 98 scan tiles */
#define WSTRIDE (NKS*8*2*512)             /* 81920 ushorts per layer */

typedef __attribute__((ext_vector_type(8))) short short8;
typedef __attribute__((ext_vector_type(4))) float floatx4;
typedef __attribute__((ext_vector_type(4))) uint uintx4;

__device__ __forceinline__ float fsilu(float x){ return x / (1.f + __expf(-x)); }
__device__ __forceinline__ ushort f2bf(float f){
  uint u = __builtin_bit_cast(uint, f);
  return (ushort)((u + 0x7FFFu + ((u >> 16) & 1u)) >> 16);
}
__device__ __forceinline__ float bf2f(ushort h){ return __builtin_bit_cast(float, ((uint)h) << 16); }
__device__ __forceinline__ uint bu(float f){ return __builtin_bit_cast(uint, f); }
__device__ __forceinline__ uint pkbf(float lo, float hi){
  return __builtin_amdgcn_perm(bu(hi), bu(lo), 0x07060302u);  // truncating bf16x2 pack
}

// ---------------- small utility kernels ----------------
__global__ __launch_bounds__(256) void k_zero_i(int* __restrict__ p, int n){
  int i = blockIdx.x*256 + threadIdx.x; if (i < n) p[i] = 0;
}
__global__ __launch_bounds__(256) void k_zero_f(float* __restrict__ p, int n){
  int i = blockIdx.x*256 + threadIdx.x; if (i < n) p[i] = 0.f;
}
__global__ __launch_bounds__(256) void k_hist(const int* __restrict__ dst, int* __restrict__ hist, int ne){
  int e = blockIdx.x*256 + threadIdx.x; if (e < ne) atomicAdd(&hist[dst[e]], 1);
}

// ---- hierarchical exclusive scan over hist[NN] -> rp, dinv ----
__global__ __launch_bounds__(256) void k_scan_a(const int* __restrict__ hist, int* __restrict__ tsum){
  __shared__ int red[4];
  const int base = blockIdx.x * TILE;
  int s = 0;
  #pragma unroll
  for (int j = 0; j < 4; ++j){
    int idx = base + threadIdx.x + j*256;
    if (idx < NN) s += hist[idx];
  }
  #pragma unroll
  for (int off = 32; off; off >>= 1) s += __shfl_down(s, off);
  if ((threadIdx.x & 63) == 0) red[threadIdx.x >> 6] = s;
  __syncthreads();
  if (threadIdx.x == 0) tsum[blockIdx.x] = red[0] + red[1] + red[2] + red[3];
}

__global__ __launch_bounds__(128) void k_scan_b(const int* __restrict__ tsum,
                                                int* __restrict__ toff, int* __restrict__ rpN){
  __shared__ int lds[128];
  const int tid = threadIdx.x;
  int v = (tid < NT) ? tsum[tid] : 0;
  lds[tid] = v; __syncthreads();
  for (int off = 1; off < 128; off <<= 1){
    int u = (tid >= off) ? lds[tid - off] : 0;
    __syncthreads();
    lds[tid] += u;
    __syncthreads();
  }
  if (tid < NT) toff[tid] = lds[tid] - v;
  if (tid == NT - 1) *rpN = lds[tid];
}

__global__ __launch_bounds__(256) void k_scan_c(const int* __restrict__ hist,
                                                const int* __restrict__ toff,
                                                int* __restrict__ rp,
                                                float* __restrict__ dinv){
  __shared__ int lds[256];
  const int tid = threadIdx.x;
  const int base = blockIdx.x * TILE + tid*4;
  int h[4]; int s = 0;
  #pragma unroll
  for (int j = 0; j < 4; ++j){ int idx = base + j; h[j] = (idx < NN) ? hist[idx] : 0; s += h[j]; }
  lds[tid] = s; __syncthreads();
  for (int off = 1; off < 256; off <<= 1){
    int u = (tid >= off) ? lds[tid - off] : 0;
    __syncthreads();
    lds[tid] += u;
    __syncthreads();
  }
  int run = toff[blockIdx.x] + lds[tid] - s;
  #pragma unroll
  for (int j = 0; j < 4; ++j){
    int idx = base + j;
    if (idx < NN){
      rp[idx] = run; run += h[j];
      dinv[idx] = rsqrtf((float)h[j] + 1.f);
    }
  }
}

// ---- chunk-private binning: each block bins its 6250 edges by dst>>6 into its own region ----
// edge packed as (src<<6) | (dst&63)
__global__ __launch_bounds__(256) void k_binA(const int* __restrict__ src, const int* __restrict__ dst,
                                              uint* __restrict__ priv, int* __restrict__ seg){
  __shared__ int hist[NB];
  __shared__ int cur[NB];
  __shared__ int scanbuf[256];
  const int c = blockIdx.x, tid = threadIdx.x;
  const size_t e0 = (size_t)c * CHUNK;
  for (int i = tid; i < NB; i += 256) hist[i] = 0;
  __syncthreads();
  for (int i = tid; i < CHUNK; i += 256) atomicAdd(&hist[dst[e0+i] >> 6], 1);
  __syncthreads();
  int loc[7]; int s = 0;
  const int base = tid * 7;
  #pragma unroll
  for (int j = 0; j < 7; ++j){ int idx = base+j; int v = (idx < NB) ? hist[idx] : 0; loc[j] = s; s += v; }
  scanbuf[tid] = s;
  __syncthreads();
  for (int off = 1; off < 256; off <<= 1){
    int u = (tid >= off) ? scanbuf[tid-off] : 0;
    __syncthreads();
    scanbuf[tid] += u;
    __syncthreads();
  }
  const int run = scanbuf[tid] - s;
  #pragma unroll
  for (int j = 0; j < 7; ++j){
    int idx = base+j;
    if (idx < NB){ int st = run + loc[j]; seg[c*(NB+1)+idx] = st; cur[idx] = st; }
  }
  if (tid == 0) seg[c*(NB+1)+NB] = CHUNK;
  __syncthreads();
  for (int i = tid; i < CHUNK; i += 256){
    const uint ss = (uint)src[e0+i], dd = (uint)dst[e0+i];
    const int p = atomicAdd(&cur[dd >> 6], 1);
    priv[(size_t)c*CHUNK + p] = (ss << 6) | (dd & 63u);
  }
}

// per bucket: scatter chunk-private edges into dst-node-sorted col via rp cursors
__global__ __launch_bounds__(256) void k_gathE2(const uint* __restrict__ priv, const int* __restrict__ seg,
                                                const int* __restrict__ rp, int* __restrict__ col){
  __shared__ int cur[64];
  const int b = blockIdx.x, tid = threadIdx.x;
  const int n0 = b * 64;
  if (tid < 64){
    const int idx = n0 + tid;
    cur[tid] = rp[(idx < NN) ? idx : NN];
  }
  __syncthreads();
  const int c = tid;
  const int s0 = seg[c*(NB+1) + b], s1 = seg[c*(NB+1) + b + 1];
  const size_t pbase = (size_t)c*CHUNK;
  for (int i = s0; i < s1; ++i){
    const uint e = priv[pbase + i];
    const int p = atomicAdd(&cur[e & 63u], 1);
    col[p] = (int)(e >> 6);
  }
}

// weights -> bf16 in per-lane MFMA fragment layout:
// frag id = q*16 + nr*2 + ks ; wimg[frag][lane*8+j] = W[col][k]
//   col = nr*16+(lane&15), k = q*64+ks*32+(lane>>4)*8+j
__global__ __launch_bounds__(256) void k_wprep(const float* __restrict__ sW, const float* __restrict__ bW,
                                               ushort* __restrict__ wimg){
  int idx = blockIdx.x*256 + threadIdx.x;
  if (idx >= NL*WSTRIDE) return;
  const int j    = idx & 7;
  const int lane = (idx >> 3) & 63;
  const int ks   = (idx >> 9) & 1;
  const int nr   = (idx >> 10) & 7;
  const int qq   = (idx >> 13) % NKS;
  const int l    = idx / (NKS << 13);
  const int colc = nr*16 + (lane & 15);
  const int kg   = qq*64 + ks*32 + (lane >> 4)*8 + j;
  const float v  = (kg < KSPL) ? sW[((size_t)l*FEAT + colc)*KSPL + kg]
                               : bW[((size_t)l*FEAT + colc)*FEAT + (kg - KSPL)];
  wimg[idx] = f2bf(v);
}

// ---------------- FKAN transform: single x-tile in LDS, inline LN/silu, 2-deep B prefetch ----------------
template <typename TIn>
__global__ __launch_bounds__(128) void k_fkan(
    const TIn* __restrict__ xin,            // [NN][128] fp32 or bf16(ushort)
    const ushort* __restrict__ wimg,        // this layer's fragment image (L2-resident)
    const float* __restrict__ ln_s, const float* __restrict__ ln_b,
    const float* __restrict__ sb, const float* __restrict__ bb,
    const float* __restrict__ dinv,
    ushort* __restrict__ hprime)
{
  __shared__ char xb[BM*256];        // x bf16 [32][128], xor-swizzled rows  (8 KB)
  __shared__ float lnS[128], lnB[128], sbias[128];

  const int tid  = threadIdx.x;
  const int lane = tid & 63, wv = tid >> 6;
  const int node0 = blockIdx.x * BM;   // NN % BM == 0: no guards anywhere

  lnS[tid] = ln_s[tid]; lnB[tid] = ln_b[tid]; sbias[tid] = sb[tid] + bb[tid];

  // ---- LN stats phase: 4 threads per node, 32 feats each; stage bf16 x in LDS ----
  const int lm = tid >> 2, part = tid & 3;
  const int node = node0 + lm;
  const uint swl = ((uint)(lm & 7)) << 4;
  char* xrow_w = xb + lm*256;
  float s1 = 0.f, s2 = 0.f;
  if constexpr (sizeof(TIn) == 4){
    const float4* xr = (const float4*)((const float*)xin + (size_t)node*FEAT + part*32);
    #pragma unroll
    for (int j = 0; j < 4; ++j){
      const float4 a = xr[2*j], b = xr[2*j+1];
      s1 += a.x+a.y+a.z+a.w + b.x+b.y+b.z+b.w;
      s2 += a.x*a.x+a.y*a.y+a.z*a.z+a.w*a.w + b.x*b.x+b.y*b.y+b.z*b.z+b.w*b.w;
      uintx4 pk;
      pk.x = pkbf(a.x, a.y); pk.y = pkbf(a.z, a.w);
      pk.z = pkbf(b.x, b.y); pk.w = pkbf(b.z, b.w);
      *(uintx4*)(xrow_w + (((uint)(part*64 + j*16)) ^ swl)) = pk;
    }
  } else {
    const uintx4* xr = (const uintx4*)((const ushort*)xin + (size_t)node*FEAT + part*32);
    #pragma unroll
    for (int j = 0; j < 4; ++j){
      const uintx4 v = xr[j];
      #pragma unroll
      for (int w = 0; w < 4; ++w){
        const float f0 = bf2f((ushort)(v[w] & 0xffff)), f1 = bf2f((ushort)(v[w] >> 16));
        s1 += f0 + f1; s2 += f0*f0 + f1*f1;
      }
      *(uintx4*)(xrow_w + (((uint)(part*64 + j*16)) ^ swl)) = v;
    }
  }
  s1 += __shfl_xor(s1, 1); s2 += __shfl_xor(s2, 1);
  s1 += __shfl_xor(s1, 2); s2 += __shfl_xor(s2, 2);
  const float mean = s1 * (1.f/128.f);
  const float var  = s2 * (1.f/128.f) - mean*mean;
  const float rsv  = rsqrtf(var + 1e-5f);
  __syncthreads();                       // xb + lnS/lnB/sbias ready -- only barrier

  // ---- MFMA K-loop: wave owns rows wv*16..+15, all 128 cols ----
  const int l15 = lane & 15, l4h = lane >> 4;
  const int row = wv*16 + l15;
  const uint swz = ((uint)(row & 7)) << 4;
  const char* xrow = xb + row*256;
  // fetch this row's LN stats from the thread that computed them (lane l15*4)
  const float mrow = __shfl(mean, (lane & 15) << 2);
  const float rrow = __shfl(rsv,  (lane & 15) << 2);

  floatx4 acc[8];
  #pragma unroll
  for (int nr = 0; nr < 8; ++nr){ floatx4 z4 = {0.f,0.f,0.f,0.f}; acc[nr] = z4; }

  const short8* w8 = (const short8*)wimg;

  auto afrag = [&](int sp)->short8 {
    const int q = sp >> 1, ks = sp & 1;
    if (q < 8){
      const int f0 = q*16 + ks*8 + l4h*2;
      const uint xx = *(const uint*)(xrow + (((uint)(f0*2)) ^ swz));
      const float x0 = bf2f((ushort)(xx & 0xffff)), x1 = bf2f((ushort)(xx >> 16));
      const float2 ls = *(const float2*)(lnS + f0);
      const float2 lb = *(const float2*)(lnB + f0);
      const float z0 = (x0 - mrow)*rrow*ls.x + lb.x;
      const float z1 = (x1 - mrow)*rrow*ls.y + lb.y;
      float e0[4], e1[4];
      #pragma unroll
      for (int g = 0; g < 4; ++g){
        const float gc = -2.f + (4.f/3.f)*(float)g;
        const float t0 = (z0 - gc)*0.75f;
        const float t1 = (z1 - gc)*0.75f;
        e0[g] = __expf(-t0*t0);
        e1[g] = __expf(-t1*t1);
      }
      uintx4 pw;
      pw.x = pkbf(e0[0], e0[1]); pw.y = pkbf(e0[2], e0[3]);
      pw.z = pkbf(e1[0], e1[1]); pw.w = pkbf(e1[2], e1[3]);
      return __builtin_bit_cast(short8, pw);
    } else {
      const int f0 = (q - 8)*64 + ks*32 + l4h*8;
      const uintx4 xx = *(const uintx4*)(xrow + (((uint)(f0*2)) ^ swz));
      uintx4 pw;
      #pragma unroll
      for (int w = 0; w < 4; ++w){
        const float x0 = bf2f((ushort)(xx[w] & 0xffff)), x1 = bf2f((ushort)(xx[w] >> 16));
        pw[w] = pkbf(fsilu(x0), fsilu(x1));
      }
      return __builtin_bit_cast(short8, pw);
    }
  };

  short8 b0[8], b1[8];
  #pragma unroll
  for (int nr = 0; nr < 8; ++nr) b0[nr] = w8[(size_t)(nr*2)*64 + lane];   // sp=0

  #pragma unroll
  for (int sp = 0; sp < 20; sp += 2){
    {   // prefetch sp+1 into b1
      const int q1 = (sp + 1) >> 1, ks1 = (sp + 1) & 1;
      #pragma unroll
      for (int nr = 0; nr < 8; ++nr) b1[nr] = w8[(size_t)(q1*16 + nr*2 + ks1)*64 + lane];
    }
    {
      const short8 af = afrag(sp);
      #pragma unroll
      for (int nr = 0; nr < 8; ++nr)
        acc[nr] = __builtin_amdgcn_mfma_f32_16x16x32_bf16(af, b0[nr], acc[nr], 0, 0, 0);
    }
    if (sp + 2 < 20){   // prefetch sp+2 into b0
      const int q2 = (sp + 2) >> 1, ks2 = (sp + 2) & 1;
      #pragma unroll
      for (int nr = 0; nr < 8; ++nr) b0[nr] = w8[(size_t)(q2*16 + nr*2 + ks2)*64 + lane];
    }
    {
      const short8 af = afrag(sp + 1);
      #pragma unroll
      for (int nr = 0; nr < 8; ++nr)
        acc[nr] = __builtin_amdgcn_mfma_f32_16x16x32_bf16(af, b1[nr], acc[nr], 0, 0, 0);
    }
  }

  // ---- epilogue: h' = dinv * (acc + bias), bf16 store ----
  const int rbase = node0 + wv*16 + l4h*4;
  float dvv[4];
  #pragma unroll
  for (int j = 0; j < 4; ++j) dvv[j] = dinv[rbase + j];
  #pragma unroll
  for (int nr = 0; nr < 8; ++nr){
    const int cf = nr*16 + l15;
    const float sv = sbias[cf];
    #pragma unroll
    for (int j = 0; j < 4; ++j)
      hprime[(size_t)(rbase + j)*FEAT + cf] = f2bf(dvv[j]*(acc[nr][j] + sv));
  }
}

// ---------------- CSR aggregation: 4 dst per wave (16-lane quarters), uint4 row gathers ----------------
__global__ __launch_bounds__(256) void k_aggD(
    const ushort* __restrict__ hprime, const int* __restrict__ rp,
    const int* __restrict__ col, const float* __restrict__ dinv,
    const float* __restrict__ gb, ushort* __restrict__ xout)
{
  const int wv = threadIdx.x >> 6, lane = threadIdx.x & 63;
  const int q4 = lane >> 4, li = lane & 15;
  const int d = blockIdx.x*16 + wv*4 + q4;    // NN = 6250*16 exactly
  const uintx4* h4 = (const uintx4*)hprime;   // row = 16 uint4 (16B per lane = 8 feats)

  const uintx4 v = h4[(size_t)d*16 + li];
  float a[8];
  #pragma unroll
  for (int w = 0; w < 4; ++w){
    a[2*w]   = bf2f((ushort)(v[w] & 0xffff));
    a[2*w+1] = bf2f((ushort)(v[w] >> 16));
  }

  const int j0 = rp[d], j1 = rp[d+1];
  int j = j0;
  for (; j + 7 < j1; j += 8){
    uintx4 w[8];
    #pragma unroll
    for (int u = 0; u < 8; ++u) w[u] = h4[(size_t)col[j+u]*16 + li];
    #pragma unroll
    for (int u = 0; u < 8; ++u)
      #pragma unroll
      for (int k = 0; k < 4; ++k){
        a[2*k]   += bf2f((ushort)(w[u][k] & 0xffff));
        a[2*k+1] += bf2f((ushort)(w[u][k] >> 16));
      }
  }
  for (; j + 3 < j1; j += 4){
    uintx4 w[4];
    #pragma unroll
    for (int u = 0; u < 4; ++u) w[u] = h4[(size_t)col[j+u]*16 + li];
    #pragma unroll
    for (int u = 0; u < 4; ++u)
      #pragma unroll
      for (int k = 0; k < 4; ++k){
        a[2*k]   += bf2f((ushort)(w[u][k] & 0xffff));
        a[2*k+1] += bf2f((ushort)(w[u][k] >> 16));
      }
  }
  for (; j < j1; ++j){
    const uintx4 w = h4[(size_t)col[j]*16 + li];
    #pragma unroll
    for (int k = 0; k < 4; ++k){
      a[2*k]   += bf2f((ushort)(w[k] & 0xffff));
      a[2*k+1] += bf2f((ushort)(w[k] >> 16));
    }
  }

  const float dv = dinv[d];
  const float4 bA = *(const float4*)(gb + li*8);
  const float4 bB = *(const float4*)(gb + li*8 + 4);
  a[0] = fsilu(dv*a[0] + bA.x); a[1] = fsilu(dv*a[1] + bA.y);
  a[2] = fsilu(dv*a[2] + bA.z); a[3] = fsilu(dv*a[3] + bA.w);
  a[4] = fsilu(dv*a[4] + bB.x); a[5] = fsilu(dv*a[5] + bB.y);
  a[6] = fsilu(dv*a[6] + bB.z); a[7] = fsilu(dv*a[7] + bB.w);
  uintx4 o;
  #pragma unroll
  for (int k = 0; k < 4; ++k)
    o[k] = (uint)f2bf(a[2*k]) | ((uint)f2bf(a[2*k+1]) << 16);
  ((uintx4*)xout)[(size_t)d*16 + li] = o;
}

// ---------------- pooling (sorted batch) ----------------
__global__ __launch_bounds__(128) void k_pool(const ushort* __restrict__ x,
                                              const int* __restrict__ batch,
                                              float* __restrict__ pooled,
                                              float* __restrict__ cnt, int n){
  const int f = threadIdx.x;
  const int start = blockIdx.x * 64;
  const int end   = min(start + 64, n);
  if (start >= end) return;
  int cur = batch[start];
  float acc = 0.f, c = 0.f;
  for (int i = start; i < end; ++i){
    const int b = batch[i];
    if (b != cur){
      atomicAdd(&pooled[(size_t)cur*FEAT + f], acc);
      if (f == 0) atomicAdd(&cnt[cur], c);
      cur = b; acc = 0.f; c = 0.f;
    }
    acc += bf2f(x[(size_t)i*FEAT + f]);
    c += 1.f;
  }
  atomicAdd(&pooled[(size_t)cur*FEAT + f], acc);
  if (f == 0) atomicAdd(&cnt[cur], c);
}

__global__ __launch_bounds__(128) void k_pool_div(float* __restrict__ pooled,
                                                  const float* __restrict__ cnt){
  const int g = blockIdx.x, f = threadIdx.x;
  pooled[(size_t)g*FEAT + f] /= fmaxf(cnt[g], 1.f);
}

// ---------------- readout FastKAN (128 -> 10) + log_softmax ----------------
__global__ __launch_bounds__(128) void k_readout(const float* __restrict__ pooled,
    const float* __restrict__ ln_s, const float* __restrict__ ln_b,
    const float* __restrict__ sW, const float* __restrict__ sb,
    const float* __restrict__ bW, const float* __restrict__ bb,
    float* __restrict__ out){
  __shared__ float cb[KSPL + FEAT];
  __shared__ float wred[2][2];
  __shared__ float outv[NCLS];
  const int tid = threadIdx.x, lane = tid & 63, wave = tid >> 6;
  const int g = blockIdx.x;

  const float xvv = pooled[(size_t)g*FEAT + tid];
  float s1 = xvv, s2 = xvv*xvv;
  #pragma unroll
  for (int off = 32; off; off >>= 1){ s1 += __shfl_down(s1, off); s2 += __shfl_down(s2, off); }
  if (lane == 0){ wred[wave][0] = s1; wred[wave][1] = s2; }
  __syncthreads();
  const float m   = (wred[0][0] + wred[1][0]) * (1.f/FEAT);
  const float var = (wred[0][1] + wred[1][1]) * (1.f/FEAT) - m*m;
  const float rs  = rsqrtf(var + 1e-5f);
  const float z   = (xvv - m) * rs * ln_s[tid] + ln_b[tid];
  #pragma unroll
  for (int gg = 0; gg < GQ; ++gg){
    const float t = (z - (-2.f + (4.f/3.f)*(float)gg)) * 0.75f;
    cb[tid*GQ + gg] = __expf(-t*t);
  }
  cb[KSPL + tid] = fsilu(xvv);
  __syncthreads();

  if (tid < NCLS){
    const float* wr = sW + (size_t)tid*KSPL;
    const float* br = bW + (size_t)tid*FEAT;
    float acc = sb[tid] + bb[tid];
    for (int k = 0; k < KSPL; ++k) acc += cb[k] * wr[k];
    for (int k = 0; k < FEAT; ++k) acc += cb[KSPL + k] * br[k];
    outv[tid] = acc;
  }
  __syncthreads();
  if (tid == 0){
    float mx = -1e30f;
    for (int o = 0; o < NCLS; ++o) mx = fmaxf(mx, outv[o]);
    float se = 0.f;
    for (int o = 0; o < NCLS; ++o) se += __expf(outv[o] - mx);
    const float lse = mx + logf(se);
    for (int o = 0; o < NCLS; ++o) out[(size_t)g*NCLS + o] = outv[o] - lse;
  }
}

extern "C" void kernel_launch(void* const* d_in, const int* in_sizes, int n_in,
                              void* d_out, int out_size, void* d_ws, size_t ws_size,
                              hipStream_t stream) {
  const float* x     = (const float*)d_in[0];
  const int*   edge  = (const int*)d_in[1];
  const int*   batch = (const int*)d_in[2];
  const float* ln_s  = (const float*)d_in[3];
  const float* ln_b  = (const float*)d_in[4];
  const float* sW    = (const float*)d_in[5];
  const float* sb    = (const float*)d_in[6];
  const float* bW    = (const float*)d_in[7];
  const float* bb    = (const float*)d_in[8];
  const float* gcn_b = (const float*)d_in[9];
  const float* ro_ln_s = (const float*)d_in[10];
  const float* ro_ln_b = (const float*)d_in[11];
  const float* ro_sW   = (const float*)d_in[12];
  const float* ro_sb   = (const float*)d_in[13];
  const float* ro_bW   = (const float*)d_in[14];
  const float* ro_bb   = (const float*)d_in[15];
  float* out = (float*)d_out;

  const int* src = edge;
  const int* dst = edge + NE;

  char* W = (char*)d_ws;
  size_t off = 0;
  auto alloc = [&](size_t bytes){ size_t r = off; off += (bytes + 1023) & ~((size_t)1023); return r; };
  float*  dinv   = (float*) (W + alloc((size_t)NN*4));
  ushort* wimg   = (ushort*)(W + alloc((size_t)NL*WSTRIDE*2));
  int*    hist   = (int*)   (W + alloc((size_t)NN*4));
  int*    rp     = (int*)   (W + alloc((size_t)(NN+1)*4));
  int*    tsum   = (int*)   (W + alloc((size_t)NT*4));
  int*    toff   = (int*)   (W + alloc((size_t)NT*4));
  uint*   priv   = (uint*)  (W + alloc((size_t)NE*4));
  int*    seg    = (int*)   (W + alloc((size_t)NCHUNK*(NB+1)*4));
  int*    col    = (int*)   (W + alloc((size_t)NE*4));
  ushort* hprime = (ushort*)(W + alloc((size_t)NN*FEAT*2));
  ushort* xcur   = (ushort*)(W + alloc((size_t)NN*FEAT*2));
  float*  pooled = (float*) (W + alloc((size_t)(NGR*FEAT + NGR)*4));
  float*  cnt    = pooled + NGR*FEAT;

  // degree norm + CSR build (layer-invariant)
  k_zero_i<<<(NN+255)/256, 256, 0, stream>>>(hist, NN);
  k_zero_f<<<(NGR*FEAT+NGR+255)/256, 256, 0, stream>>>(pooled, NGR*FEAT + NGR);
  k_hist<<<(NE+255)/256, 256, 0, stream>>>(dst, hist, NE);
  k_scan_a<<<NT, 256, 0, stream>>>(hist, tsum);
  k_scan_b<<<1, 128, 0, stream>>>(tsum, toff, rp + NN);
  k_scan_c<<<NT, 256, 0, stream>>>(hist, toff, rp, dinv);
  k_binA<<<NCHUNK, 256, 0, stream>>>(src, dst, priv, seg);
  k_gathE2<<<NB, 256, 0, stream>>>(priv, seg, rp, col);
  k_wprep<<<(NL*WSTRIDE + 255)/256, 256, 0, stream>>>(sW, bW, wimg);

  const int fkan_grid = NN / BM;
  for (int l = 0; l < NL; ++l){
    const ushort* wl = wimg + (size_t)l*WSTRIDE;
    if (l == 0)
      k_fkan<float><<<fkan_grid, 128, 0, stream>>>(x, wl,
          ln_s + l*FEAT, ln_b + l*FEAT, sb + l*FEAT, bb + l*FEAT, dinv, hprime);
    else
      k_fkan<ushort><<<fkan_grid, 128, 0, stream>>>(xcur, wl,
          ln_s + l*FEAT, ln_b + l*FEAT, sb + l*FEAT, bb + l*FEAT, dinv, hprime);
    k_aggD<<<NN/16, 256, 0, stream>>>(hprime, rp, col, dinv, gcn_b + l*FEAT, xcur);
  }

  k_pool<<<(NN+63)/64, 128, 0, stream>>>(xcur, batch, pooled, cnt, NN);
  k_pool_div<<<NGR, 128, 0, stream>>>(pooled, cnt);
  k_readout<<<NGR, 128, 0, stream>>>(pooled, ro_ln_s, ro_ln_b,
                                     ro_sW, ro_sb, ro_bW, ro_bb, out);
}

// Round 17
// 477.609 us; speedup vs baseline: 1.1089x; 1.0018x over previous
//
#include <hip/hip_runtime.h>
#include <math.h>

#define NN     100000
#define NE     1600000
#define FEAT   128
#define GQ     4
#define NL     3
#define NGR    64
#define NCLS   10
#define KSPL   512
#define NKS    10            /* K-steps of 64 (640 total) */
#define BM     32            /* nodes per block (128 threads, 2 waves) */
#define NB     1563          /* dst buckets of 64 nodes: ceil(NN/64) */
#define NCHUNK 256
#define CHUNK  6250          /* NE / NCHUNK */
#define TILE   1024
#define NT     ((NN + TILE - 1) / TILE)   /* 98 scan tiles */
#define WSTRIDE (NKS*8*2*512)             /* 81920 ushorts per layer */

typedef __attribute__((ext_vector_type(8))) short short8;
typedef __attribute__((ext_vector_type(4))) float floatx4;
typedef __attribute__((ext_vector_type(4))) uint uintx4;

__device__ __forceinline__ float fsilu(float x){ return x / (1.f + __expf(-x)); }
__device__ __forceinline__ ushort f2bf(float f){
  uint u = __builtin_bit_cast(uint, f);
  return (ushort)((u + 0x7FFFu + ((u >> 16) & 1u)) >> 16);
}
__device__ __forceinline__ float bf2f(ushort h){ return __builtin_bit_cast(float, ((uint)h) << 16); }
__device__ __forceinline__ uint bu(float f){ return __builtin_bit_cast(uint, f); }
__device__ __forceinline__ uint pkbf(float lo, float hi){
  return __builtin_amdgcn_perm(bu(hi), bu(lo), 0x07060302u);  // truncating bf16x2 pack
}

// ---------------- small utility kernels ----------------
__global__ __launch_bounds__(256) void k_zero_i(int* __restrict__ p, int n){
  int i = blockIdx.x*256 + threadIdx.x; if (i < n) p[i] = 0;
}
__global__ __launch_bounds__(256) void k_zero_f(float* __restrict__ p, int n){
  int i = blockIdx.x*256 + threadIdx.x; if (i < n) p[i] = 0.f;
}
__global__ __launch_bounds__(256) void k_hist(const int* __restrict__ dst, int* __restrict__ hist, int ne){
  int e = blockIdx.x*256 + threadIdx.x; if (e < ne) atomicAdd(&hist[dst[e]], 1);
}

// ---- hierarchical exclusive scan over hist[NN] -> rp, dinv ----
__global__ __launch_bounds__(256) void k_scan_a(const int* __restrict__ hist, int* __restrict__ tsum){
  __shared__ int red[4];
  const int base = blockIdx.x * TILE;
  int s = 0;
  #pragma unroll
  for (int j = 0; j < 4; ++j){
    int idx = base + threadIdx.x + j*256;
    if (idx < NN) s += hist[idx];
  }
  #pragma unroll
  for (int off = 32; off; off >>= 1) s += __shfl_down(s, off);
  if ((threadIdx.x & 63) == 0) red[threadIdx.x >> 6] = s;
  __syncthreads();
  if (threadIdx.x == 0) tsum[blockIdx.x] = red[0] + red[1] + red[2] + red[3];
}

__global__ __launch_bounds__(128) void k_scan_b(const int* __restrict__ tsum,
                                                int* __restrict__ toff, int* __restrict__ rpN){
  __shared__ int lds[128];
  const int tid = threadIdx.x;
  int v = (tid < NT) ? tsum[tid] : 0;
  lds[tid] = v; __syncthreads();
  for (int off = 1; off < 128; off <<= 1){
    int u = (tid >= off) ? lds[tid - off] : 0;
    __syncthreads();
    lds[tid] += u;
    __syncthreads();
  }
  if (tid < NT) toff[tid] = lds[tid] - v;
  if (tid == NT - 1) *rpN = lds[tid];
}

__global__ __launch_bounds__(256) void k_scan_c(const int* __restrict__ hist,
                                                const int* __restrict__ toff,
                                                int* __restrict__ rp,
                                                float* __restrict__ dinv){
  __shared__ int lds[256];
  const int tid = threadIdx.x;
  const int base = blockIdx.x * TILE + tid*4;
  int h[4]; int s = 0;
  #pragma unroll
  for (int j = 0; j < 4; ++j){ int idx = base + j; h[j] = (idx < NN) ? hist[idx] : 0; s += h[j]; }
  lds[tid] = s; __syncthreads();
  for (int off = 1; off < 256; off <<= 1){
    int u = (tid >= off) ? lds[tid - off] : 0;
    __syncthreads();
    lds[tid] += u;
    __syncthreads();
  }
  int run = toff[blockIdx.x] + lds[tid] - s;
  #pragma unroll
  for (int j = 0; j < 4; ++j){
    int idx = base + j;
    if (idx < NN){
      rp[idx] = run; run += h[j];
      dinv[idx] = rsqrtf((float)h[j] + 1.f);
    }
  }
}

// ---- chunk-private binning: each block bins its 6250 edges by dst>>6 into its own region ----
// edge packed as (src<<6) | (dst&63)
__global__ __launch_bounds__(256) void k_binA(const int* __restrict__ src, const int* __restrict__ dst,
                                              uint* __restrict__ priv, int* __restrict__ seg){
  __shared__ int hist[NB];
  __shared__ int cur[NB];
  __shared__ int scanbuf[256];
  const int c = blockIdx.x, tid = threadIdx.x;
  const size_t e0 = (size_t)c * CHUNK;
  for (int i = tid; i < NB; i += 256) hist[i] = 0;
  __syncthreads();
  for (int i = tid; i < CHUNK; i += 256) atomicAdd(&hist[dst[e0+i] >> 6], 1);
  __syncthreads();
  int loc[7]; int s = 0;
  const int base = tid * 7;
  #pragma unroll
  for (int j = 0; j < 7; ++j){ int idx = base+j; int v = (idx < NB) ? hist[idx] : 0; loc[j] = s; s += v; }
  scanbuf[tid] = s;
  __syncthreads();
  for (int off = 1; off < 256; off <<= 1){
    int u = (tid >= off) ? scanbuf[tid-off] : 0;
    __syncthreads();
    scanbuf[tid] += u;
    __syncthreads();
  }
  const int run = scanbuf[tid] - s;
  #pragma unroll
  for (int j = 0; j < 7; ++j){
    int idx = base+j;
    if (idx < NB){ int st = run + loc[j]; seg[c*(NB+1)+idx] = st; cur[idx] = st; }
  }
  if (tid == 0) seg[c*(NB+1)+NB] = CHUNK;
  __syncthreads();
  for (int i = tid; i < CHUNK; i += 256){
    const uint ss = (uint)src[e0+i], dd = (uint)dst[e0+i];
    const int p = atomicAdd(&cur[dd >> 6], 1);
    priv[(size_t)c*CHUNK + p] = (ss << 6) | (dd & 63u);
  }
}

// per bucket: scatter chunk-private edges into dst-node-sorted col via rp cursors
__global__ __launch_bounds__(256) void k_gathE2(const uint* __restrict__ priv, const int* __restrict__ seg,
                                                const int* __restrict__ rp, int* __restrict__ col){
  __shared__ int cur[64];
  const int b = blockIdx.x, tid = threadIdx.x;
  const int n0 = b * 64;
  if (tid < 64){
    const int idx = n0 + tid;
    cur[tid] = rp[(idx < NN) ? idx : NN];
  }
  __syncthreads();
  const int c = tid;
  const int s0 = seg[c*(NB+1) + b], s1 = seg[c*(NB+1) + b + 1];
  const size_t pbase = (size_t)c*CHUNK;
  for (int i = s0; i < s1; ++i){
    const uint e = priv[pbase + i];
    const int p = atomicAdd(&cur[e & 63u], 1);
    col[p] = (int)(e >> 6);
  }
}

// weights -> bf16 in per-lane MFMA fragment layout:
// frag id = q*16 + nr*2 + ks ; wimg[frag][lane*8+j] = W[col][k]
//   col = nr*16+(lane&15), k = q*64+ks*32+(lane>>4)*8+j
__global__ __launch_bounds__(256) void k_wprep(const float* __restrict__ sW, const float* __restrict__ bW,
                                               ushort* __restrict__ wimg){
  int idx = blockIdx.x*256 + threadIdx.x;
  if (idx >= NL*WSTRIDE) return;
  const int j    = idx & 7;
  const int lane = (idx >> 3) & 63;
  const int ks   = (idx >> 9) & 1;
  const int nr   = (idx >> 10) & 7;
  const int qq   = (idx >> 13) % NKS;
  const int l    = idx / (NKS << 13);
  const int colc = nr*16 + (lane & 15);
  const int kg   = qq*64 + ks*32 + (lane >> 4)*8 + j;
  const float v  = (kg < KSPL) ? sW[((size_t)l*FEAT + colc)*KSPL + kg]
                               : bW[((size_t)l*FEAT + colc)*FEAT + (kg - KSPL)];
  wimg[idx] = f2bf(v);
}

// ---------------- FKAN transform: single x-tile in LDS, inline LN/silu, 2-deep B prefetch ----------------
template <typename TIn>
__global__ __launch_bounds__(128) void k_fkan(
    const TIn* __restrict__ xin,            // [NN][128] fp32 or bf16(ushort)
    const ushort* __restrict__ wimg,        // this layer's fragment image (L2-resident)
    const float* __restrict__ ln_s, const float* __restrict__ ln_b,
    const float* __restrict__ sb, const float* __restrict__ bb,
    const float* __restrict__ dinv,
    ushort* __restrict__ hprime)
{
  __shared__ char xb[BM*256];        // x bf16 [32][128], xor-swizzled rows  (8 KB)
  __shared__ float lnS[128], lnB[128], sbias[128];

  const int tid  = threadIdx.x;
  const int lane = tid & 63, wv = tid >> 6;
  const int node0 = blockIdx.x * BM;   // NN % BM == 0: no guards anywhere

  lnS[tid] = ln_s[tid]; lnB[tid] = ln_b[tid]; sbias[tid] = sb[tid] + bb[tid];

  // ---- LN stats phase: 4 threads per node, 32 feats each; stage bf16 x in LDS ----
  const int lm = tid >> 2, part = tid & 3;
  const int node = node0 + lm;
  const uint swl = ((uint)(lm & 7)) << 4;
  char* xrow_w = xb + lm*256;
  float s1 = 0.f, s2 = 0.f;
  if constexpr (sizeof(TIn) == 4){
    const float4* xr = (const float4*)((const float*)xin + (size_t)node*FEAT + part*32);
    #pragma unroll
    for (int j = 0; j < 4; ++j){
      const float4 a = xr[2*j], b = xr[2*j+1];
      s1 += a.x+a.y+a.z+a.w + b.x+b.y+b.z+b.w;
      s2 += a.x*a.x+a.y*a.y+a.z*a.z+a.w*a.w + b.x*b.x+b.y*b.y+b.z*b.z+b.w*b.w;
      uintx4 pk;
      pk.x = pkbf(a.x, a.y); pk.y = pkbf(a.z, a.w);
      pk.z = pkbf(b.x, b.y); pk.w = pkbf(b.z, b.w);
      *(uintx4*)(xrow_w + (((uint)(part*64 + j*16)) ^ swl)) = pk;
    }
  } else {
    const uintx4* xr = (const uintx4*)((const ushort*)xin + (size_t)node*FEAT + part*32);
    #pragma unroll
    for (int j = 0; j < 4; ++j){
      const uintx4 v = xr[j];
      #pragma unroll
      for (int w = 0; w < 4; ++w){
        const float f0 = bf2f((ushort)(v[w] & 0xffff)), f1 = bf2f((ushort)(v[w] >> 16));
        s1 += f0 + f1; s2 += f0*f0 + f1*f1;
      }
      *(uintx4*)(xrow_w + (((uint)(part*64 + j*16)) ^ swl)) = v;
    }
  }
  s1 += __shfl_xor(s1, 1); s2 += __shfl_xor(s2, 1);
  s1 += __shfl_xor(s1, 2); s2 += __shfl_xor(s2, 2);
  const float mean = s1 * (1.f/128.f);
  const float var  = s2 * (1.f/128.f) - mean*mean;
  const float rsv  = rsqrtf(var + 1e-5f);
  __syncthreads();                       // xb + lnS/lnB/sbias ready -- only barrier

  // ---- MFMA K-loop: wave owns rows wv*16..+15, all 128 cols ----
  const int l15 = lane & 15, l4h = lane >> 4;
  const int row = wv*16 + l15;
  const uint swz = ((uint)(row & 7)) << 4;
  const char* xrow = xb + row*256;
  // fetch this row's LN stats from the thread that computed them (lane l15*4)
  const float mrow = __shfl(mean, (lane & 15) << 2);
  const float rrow = __shfl(rsv,  (lane & 15) << 2);

  floatx4 acc[8];
  #pragma unroll
  for (int nr = 0; nr < 8; ++nr){ floatx4 z4 = {0.f,0.f,0.f,0.f}; acc[nr] = z4; }

  const short8* w8 = (const short8*)wimg;

  auto afrag = [&](int sp)->short8 {
    const int q = sp >> 1, ks = sp & 1;
    if (q < 8){
      const int f0 = q*16 + ks*8 + l4h*2;
      const uint xx = *(const uint*)(xrow + (((uint)(f0*2)) ^ swz));
      const float x0 = bf2f((ushort)(xx & 0xffff)), x1 = bf2f((ushort)(xx >> 16));
      const float2 ls = *(const float2*)(lnS + f0);
      const float2 lb = *(const float2*)(lnB + f0);
      const float z0 = (x0 - mrow)*rrow*ls.x + lb.x;
      const float z1 = (x1 - mrow)*rrow*ls.y + lb.y;
      float e0[4], e1[4];
      #pragma unroll
      for (int g = 0; g < 4; ++g){
        const float gc = -2.f + (4.f/3.f)*(float)g;
        const float t0 = (z0 - gc)*0.75f;
        const float t1 = (z1 - gc)*0.75f;
        e0[g] = __expf(-t0*t0);
        e1[g] = __expf(-t1*t1);
      }
      uintx4 pw;
      pw.x = pkbf(e0[0], e0[1]); pw.y = pkbf(e0[2], e0[3]);
      pw.z = pkbf(e1[0], e1[1]); pw.w = pkbf(e1[2], e1[3]);
      return __builtin_bit_cast(short8, pw);
    } else {
      const int f0 = (q - 8)*64 + ks*32 + l4h*8;
      const uintx4 xx = *(const uintx4*)(xrow + (((uint)(f0*2)) ^ swz));
      uintx4 pw;
      #pragma unroll
      for (int w = 0; w < 4; ++w){
        const float x0 = bf2f((ushort)(xx[w] & 0xffff)), x1 = bf2f((ushort)(xx[w] >> 16));
        pw[w] = pkbf(fsilu(x0), fsilu(x1));
      }
      return __builtin_bit_cast(short8, pw);
    }
  };

  short8 b0[8], b1[8];
  #pragma unroll
  for (int nr = 0; nr < 8; ++nr) b0[nr] = w8[(size_t)(nr*2)*64 + lane];   // sp=0

  #pragma unroll
  for (int sp = 0; sp < 20; sp += 2){
    {   // prefetch sp+1 into b1
      const int q1 = (sp + 1) >> 1, ks1 = (sp + 1) & 1;
      #pragma unroll
      for (int nr = 0; nr < 8; ++nr) b1[nr] = w8[(size_t)(q1*16 + nr*2 + ks1)*64 + lane];
    }
    {
      const short8 af = afrag(sp);
      #pragma unroll
      for (int nr = 0; nr < 8; ++nr)
        acc[nr] = __builtin_amdgcn_mfma_f32_16x16x32_bf16(af, b0[nr], acc[nr], 0, 0, 0);
    }
    if (sp + 2 < 20){   // prefetch sp+2 into b0
      const int q2 = (sp + 2) >> 1, ks2 = (sp + 2) & 1;
      #pragma unroll
      for (int nr = 0; nr < 8; ++nr) b0[nr] = w8[(size_t)(q2*16 + nr*2 + ks2)*64 + lane];
    }
    {
      const short8 af = afrag(sp + 1);
      #pragma unroll
      for (int nr = 0; nr < 8; ++nr)
        acc[nr] = __builtin_amdgcn_mfma_f32_16x16x32_bf16(af, b1[nr], acc[nr], 0, 0, 0);
    }
  }

  // ---- epilogue: h' = dinv * (acc + bias), bf16 store ----
  const int rbase = node0 + wv*16 + l4h*4;
  float dvv[4];
  #pragma unroll
  for (int j = 0; j < 4; ++j) dvv[j] = dinv[rbase + j];
  #pragma unroll
  for (int nr = 0; nr < 8; ++nr){
    const int cf = nr*16 + l15;
    const float sv = sbias[cf];
    #pragma unroll
    for (int j = 0; j < 4; ++j)
      hprime[(size_t)(rbase + j)*FEAT + cf] = f2bf(dvv[j]*(acc[nr][j] + sv));
  }
}

// ---------------- CSR aggregation: 2 dst per wave (32-lane halves), uint2 row gathers ----------------
__global__ __launch_bounds__(256) void k_aggD(
    const ushort* __restrict__ hprime, const int* __restrict__ rp,
    const int* __restrict__ col, const float* __restrict__ dinv,
    const float* __restrict__ gb, ushort* __restrict__ xout)
{
  const int wv = threadIdx.x >> 6, lane = threadIdx.x & 63;
  const int half = lane >> 5, li = lane & 31;
  const int d = blockIdx.x*8 + wv*2 + half;   // NN = 12500*8 exactly
  const uint2* h2 = (const uint2*)hprime;     // row = 32 uint2 (8B per lane covers 4 feats)

  const uint2 v = h2[(size_t)d*32 + li];
  float a0 = bf2f((ushort)(v.x & 0xffff)), a1 = bf2f((ushort)(v.x >> 16));
  float a2 = bf2f((ushort)(v.y & 0xffff)), a3 = bf2f((ushort)(v.y >> 16));

  const int j0 = rp[d], j1 = rp[d+1];
  int j = j0;
  for (; j + 7 < j1; j += 8){
    uint2 w[8];
    #pragma unroll
    for (int u = 0; u < 8; ++u) w[u] = h2[(size_t)col[j+u]*32 + li];
    #pragma unroll
    for (int u = 0; u < 8; ++u){
      a0 += bf2f((ushort)(w[u].x & 0xffff)); a1 += bf2f((ushort)(w[u].x >> 16));
      a2 += bf2f((ushort)(w[u].y & 0xffff)); a3 += bf2f((ushort)(w[u].y >> 16));
    }
  }
  for (; j + 3 < j1; j += 4){
    uint2 w[4];
    #pragma unroll
    for (int u = 0; u < 4; ++u) w[u] = h2[(size_t)col[j+u]*32 + li];
    #pragma unroll
    for (int u = 0; u < 4; ++u){
      a0 += bf2f((ushort)(w[u].x & 0xffff)); a1 += bf2f((ushort)(w[u].x >> 16));
      a2 += bf2f((ushort)(w[u].y & 0xffff)); a3 += bf2f((ushort)(w[u].y >> 16));
    }
  }
  for (; j < j1; ++j){
    const uint2 w = h2[(size_t)col[j]*32 + li];
    a0 += bf2f((ushort)(w.x & 0xffff)); a1 += bf2f((ushort)(w.x >> 16));
    a2 += bf2f((ushort)(w.y & 0xffff)); a3 += bf2f((ushort)(w.y >> 16));
  }

  const float dv = dinv[d];
  const float4 b4 = *(const float4*)(gb + li*4);
  a0 = fsilu(dv*a0 + b4.x);
  a1 = fsilu(dv*a1 + b4.y);
  a2 = fsilu(dv*a2 + b4.z);
  a3 = fsilu(dv*a3 + b4.w);
  uint2 o;
  o.x = (uint)f2bf(a0) | ((uint)f2bf(a1) << 16);
  o.y = (uint)f2bf(a2) | ((uint)f2bf(a3) << 16);
  ((uint2*)xout)[(size_t)d*32 + li] = o;
}

// ---------------- pooling (sorted batch) ----------------
__global__ __launch_bounds__(128) void k_pool(const ushort* __restrict__ x,
                                              const int* __restrict__ batch,
                                              float* __restrict__ pooled,
                                              float* __restrict__ cnt, int n){
  const int f = threadIdx.x;
  const int start = blockIdx.x * 64;
  const int end   = min(start + 64, n);
  if (start >= end) return;
  int cur = batch[start];
  float acc = 0.f, c = 0.f;
  for (int i = start; i < end; ++i){
    const int b = batch[i];
    if (b != cur){
      atomicAdd(&pooled[(size_t)cur*FEAT + f], acc);
      if (f == 0) atomicAdd(&cnt[cur], c);
      cur = b; acc = 0.f; c = 0.f;
    }
    acc += bf2f(x[(size_t)i*FEAT + f]);
    c += 1.f;
  }
  atomicAdd(&pooled[(size_t)cur*FEAT + f], acc);
  if (f == 0) atomicAdd(&cnt[cur], c);
}

__global__ __launch_bounds__(128) void k_pool_div(float* __restrict__ pooled,
                                                  const float* __restrict__ cnt){
  const int g = blockIdx.x, f = threadIdx.x;
  pooled[(size_t)g*FEAT + f] /= fmaxf(cnt[g], 1.f);
}

// ---------------- readout FastKAN (128 -> 10) + log_softmax ----------------
__global__ __launch_bounds__(128) void k_readout(const float* __restrict__ pooled,
    const float* __restrict__ ln_s, const float* __restrict__ ln_b,
    const float* __restrict__ sW, const float* __restrict__ sb,
    const float* __restrict__ bW, const float* __restrict__ bb,
    float* __restrict__ out){
  __shared__ float cb[KSPL + FEAT];
  __shared__ float wred[2][2];
  __shared__ float outv[NCLS];
  const int tid = threadIdx.x, lane = tid & 63, wave = tid >> 6;
  const int g = blockIdx.x;

  const float xvv = pooled[(size_t)g*FEAT + tid];
  float s1 = xvv, s2 = xvv*xvv;
  #pragma unroll
  for (int off = 32; off; off >>= 1){ s1 += __shfl_down(s1, off); s2 += __shfl_down(s2, off); }
  if (lane == 0){ wred[wave][0] = s1; wred[wave][1] = s2; }
  __syncthreads();
  const float m   = (wred[0][0] + wred[1][0]) * (1.f/FEAT);
  const float var = (wred[0][1] + wred[1][1]) * (1.f/FEAT) - m*m;
  const float rs  = rsqrtf(var + 1e-5f);
  const float z   = (xvv - m) * rs * ln_s[tid] + ln_b[tid];
  #pragma unroll
  for (int gg = 0; gg < GQ; ++gg){
    const float t = (z - (-2.f + (4.f/3.f)*(float)gg)) * 0.75f;
    cb[tid*GQ + gg] = __expf(-t*t);
  }
  cb[KSPL + tid] = fsilu(xvv);
  __syncthreads();

  if (tid < NCLS){
    const float* wr = sW + (size_t)tid*KSPL;
    const float* br = bW + (size_t)tid*FEAT;
    float acc = sb[tid] + bb[tid];
    for (int k = 0; k < KSPL; ++k) acc += cb[k] * wr[k];
    for (int k = 0; k < FEAT; ++k) acc += cb[KSPL + k] * br[k];
    outv[tid] = acc;
  }
  __syncthreads();
  if (tid == 0){
    float mx = -1e30f;
    for (int o = 0; o < NCLS; ++o) mx = fmaxf(mx, outv[o]);
    float se = 0.f;
    for (int o = 0; o < NCLS; ++o) se += __expf(outv[o] - mx);
    const float lse = mx + logf(se);
    for (int o = 0; o < NCLS; ++o) out[(size_t)g*NCLS + o] = outv[o] - lse;
  }
}

extern "C" void kernel_launch(void* const* d_in, const int* in_sizes, int n_in,
                              void* d_out, int out_size, void* d_ws, size_t ws_size,
                              hipStream_t stream) {
  const float* x     = (const float*)d_in[0];
  const int*   edge  = (const int*)d_in[1];
  const int*   batch = (const int*)d_in[2];
  const float* ln_s  = (const float*)d_in[3];
  const float* ln_b  = (const float*)d_in[4];
  const float* sW    = (const float*)d_in[5];
  const float* sb    = (const float*)d_in[6];
  const float* bW    = (const float*)d_in[7];
  const float* bb    = (const float*)d_in[8];
  const float* gcn_b = (const float*)d_in[9];
  const float* ro_ln_s = (const float*)d_in[10];
  const float* ro_ln_b = (const float*)d_in[11];
  const float* ro_sW   = (const float*)d_in[12];
  const float* ro_sb   = (const float*)d_in[13];
  const float* ro_bW   = (const float*)d_in[14];
  const float* ro_bb   = (const float*)d_in[15];
  float* out = (float*)d_out;

  const int* src = edge;
  const int* dst = edge + NE;

  char* W = (char*)d_ws;
  size_t off = 0;
  auto alloc = [&](size_t bytes){ size_t r = off; off += (bytes + 1023) & ~((size_t)1023); return r; };
  float*  dinv   = (float*) (W + alloc((size_t)NN*4));
  ushort* wimg   = (ushort*)(W + alloc((size_t)NL*WSTRIDE*2));
  int*    hist   = (int*)   (W + alloc((size_t)NN*4));
  int*    rp     = (int*)   (W + alloc((size_t)(NN+1)*4));
  int*    tsum   = (int*)   (W + alloc((size_t)NT*4));
  int*    toff   = (int*)   (W + alloc((size_t)NT*4));
  uint*   priv   = (uint*)  (W + alloc((size_t)NE*4));
  int*    seg    = (int*)   (W + alloc((size_t)NCHUNK*(NB+1)*4));
  int*    col    = (int*)   (W + alloc((size_t)NE*4));
  ushort* hprime = (ushort*)(W + alloc((size_t)NN*FEAT*2));
  ushort* xcur   = (ushort*)(W + alloc((size_t)NN*FEAT*2));
  float*  pooled = (float*) (W + alloc((size_t)(NGR*FEAT + NGR)*4));
  float*  cnt    = pooled + NGR*FEAT;

  // degree norm + CSR build (layer-invariant)
  k_zero_i<<<(NN+255)/256, 256, 0, stream>>>(hist, NN);
  k_zero_f<<<(NGR*FEAT+NGR+255)/256, 256, 0, stream>>>(pooled, NGR*FEAT + NGR);
  k_hist<<<(NE+255)/256, 256, 0, stream>>>(dst, hist, NE);
  k_scan_a<<<NT, 256, 0, stream>>>(hist, tsum);
  k_scan_b<<<1, 128, 0, stream>>>(tsum, toff, rp + NN);
  k_scan_c<<<NT, 256, 0, stream>>>(hist, toff, rp, dinv);
  k_binA<<<NCHUNK, 256, 0, stream>>>(src, dst, priv, seg);
  k_gathE2<<<NB, 256, 0, stream>>>(priv, seg, rp, col);
  k_wprep<<<(NL*WSTRIDE + 255)/256, 256, 0, stream>>>(sW, bW, wimg);

  const int fkan_grid = NN / BM;
  for (int l = 0; l < NL; ++l){
    const ushort* wl = wimg + (size_t)l*WSTRIDE;
    if (l == 0)
      k_fkan<float><<<fkan_grid, 128, 0, stream>>>(x, wl,
          ln_s + l*FEAT, ln_b + l*FEAT, sb + l*FEAT, bb + l*FEAT, dinv, hprime);
    else
      k_fkan<ushort><<<fkan_grid, 128, 0, stream>>>(xcur, wl,
          ln_s + l*FEAT, ln_b + l*FEAT, sb + l*FEAT, bb + l*FEAT, dinv, hprime);
    k_aggD<<<NN/8, 256, 0, stream>>>(hprime, rp, col, dinv, gcn_b + l*FEAT, xcur);
  }

  k_pool<<<(NN+63)/64, 128, 0, stream>>>(xcur, batch, pooled, cnt, NN);
  k_pool_div<<<NGR, 128, 0, stream>>>(pooled, cnt);
  k_readout<<<NGR, 128, 0, stream>>>(pooled, ro_ln_s, ro_ln_b,
                                     ro_sW, ro_sb, ro_bW, ro_bb, out);
}

// Round 18
// 416.176 us; speedup vs baseline: 1.2726x; 1.1476x over previous
//
#include <hip/hip_runtime.h>
#include <math.h>

#define NN     100000
#define NE     1600000
#define FEAT   128
#define GQ     4
#define NL     3
#define NGR    64
#define NCLS   10
#define KSPL   512
#define NKS    10            /* K-steps of 64 (640 total) */
#define BM     32            /* nodes per block (128 threads, 2 waves) */
#define NB     1563          /* dst buckets of 64 nodes: ceil(NN/64) */
#define NCHUNK 256
#define CHUNK  6250          /* NE / NCHUNK */
#define TILE   1024
#define NT     ((NN + TILE - 1) / TILE)   /* 98 scan tiles */
#define WSTRIDE (NKS*8*2*512)             /* 81920 ushorts per layer */

typedef __attribute__((ext_vector_type(8))) short short8;
typedef __attribute__((ext_vector_type(4))) float floatx4;
typedef __attribute__((ext_vector_type(2))) float floatx2;
typedef __attribute__((ext_vector_type(4))) uint uintx4;

__device__ __forceinline__ float fsilu(float x){ return x / (1.f + __expf(-x)); }
__device__ __forceinline__ ushort f2bf(float f){
  uint u = __builtin_bit_cast(uint, f);
  return (ushort)((u + 0x7FFFu + ((u >> 16) & 1u)) >> 16);
}
__device__ __forceinline__ float bf2f(ushort h){ return __builtin_bit_cast(float, ((uint)h) << 16); }
__device__ __forceinline__ uint bu(float f){ return __builtin_bit_cast(uint, f); }
__device__ __forceinline__ uint pkbf(float lo, float hi){
  return __builtin_amdgcn_perm(bu(hi), bu(lo), 0x07060302u);  // truncating bf16x2 pack
}

// ---------------- small utility kernels ----------------
__global__ __launch_bounds__(256) void k_zero_i(int* __restrict__ p, int n){
  int i = blockIdx.x*256 + threadIdx.x; if (i < n) p[i] = 0;
}
__global__ __launch_bounds__(256) void k_zero_f(float* __restrict__ p, int n){
  int i = blockIdx.x*256 + threadIdx.x; if (i < n) p[i] = 0.f;
}
__global__ __launch_bounds__(256) void k_hist(const int* __restrict__ dst, int* __restrict__ hist, int ne){
  int e = blockIdx.x*256 + threadIdx.x; if (e < ne) atomicAdd(&hist[dst[e]], 1);
}

// ---- hierarchical exclusive scan over hist[NN] -> rp, dinv ----
__global__ __launch_bounds__(256) void k_scan_a(const int* __restrict__ hist, int* __restrict__ tsum){
  __shared__ int red[4];
  const int base = blockIdx.x * TILE;
  int s = 0;
  #pragma unroll
  for (int j = 0; j < 4; ++j){
    int idx = base + threadIdx.x + j*256;
    if (idx < NN) s += hist[idx];
  }
  #pragma unroll
  for (int off = 32; off; off >>= 1) s += __shfl_down(s, off);
  if ((threadIdx.x & 63) == 0) red[threadIdx.x >> 6] = s;
  __syncthreads();
  if (threadIdx.x == 0) tsum[blockIdx.x] = red[0] + red[1] + red[2] + red[3];
}

__global__ __launch_bounds__(128) void k_scan_b(const int* __restrict__ tsum,
                                                int* __restrict__ toff, int* __restrict__ rpN){
  __shared__ int lds[128];
  const int tid = threadIdx.x;
  int v = (tid < NT) ? tsum[tid] : 0;
  lds[tid] = v; __syncthreads();
  for (int off = 1; off < 128; off <<= 1){
    int u = (tid >= off) ? lds[tid - off] : 0;
    __syncthreads();
    lds[tid] += u;
    __syncthreads();
  }
  if (tid < NT) toff[tid] = lds[tid] - v;
  if (tid == NT - 1) *rpN = lds[tid];
}

__global__ __launch_bounds__(256) void k_scan_c(const int* __restrict__ hist,
                                                const int* __restrict__ toff,
                                                int* __restrict__ rp,
                                                float* __restrict__ dinv){
  __shared__ int lds[256];
  const int tid = threadIdx.x;
  const int base = blockIdx.x * TILE + tid*4;
  int h[4]; int s = 0;
  #pragma unroll
  for (int j = 0; j < 4; ++j){ int idx = base + j; h[j] = (idx < NN) ? hist[idx] : 0; s += h[j]; }
  lds[tid] = s; __syncthreads();
  for (int off = 1; off < 256; off <<= 1){
    int u = (tid >= off) ? lds[tid - off] : 0;
    __syncthreads();
    lds[tid] += u;
    __syncthreads();
  }
  int run = toff[blockIdx.x] + lds[tid] - s;
  #pragma unroll
  for (int j = 0; j < 4; ++j){
    int idx = base + j;
    if (idx < NN){
      rp[idx] = run; run += h[j];
      dinv[idx] = rsqrtf((float)h[j] + 1.f);
    }
  }
}

// ---- chunk-private binning: each block bins its 6250 edges by dst>>6 into its own region ----
// edge packed as (src<<6) | (dst&63)
__global__ __launch_bounds__(256) void k_binA(const int* __restrict__ src, const int* __restrict__ dst,
                                              uint* __restrict__ priv, int* __restrict__ seg){
  __shared__ int hist[NB];
  __shared__ int cur[NB];
  __shared__ int scanbuf[256];
  const int c = blockIdx.x, tid = threadIdx.x;
  const size_t e0 = (size_t)c * CHUNK;
  for (int i = tid; i < NB; i += 256) hist[i] = 0;
  __syncthreads();
  for (int i = tid; i < CHUNK; i += 256) atomicAdd(&hist[dst[e0+i] >> 6], 1);
  __syncthreads();
  int loc[7]; int s = 0;
  const int base = tid * 7;
  #pragma unroll
  for (int j = 0; j < 7; ++j){ int idx = base+j; int v = (idx < NB) ? hist[idx] : 0; loc[j] = s; s += v; }
  scanbuf[tid] = s;
  __syncthreads();
  for (int off = 1; off < 256; off <<= 1){
    int u = (tid >= off) ? scanbuf[tid-off] : 0;
    __syncthreads();
    scanbuf[tid] += u;
    __syncthreads();
  }
  const int run = scanbuf[tid] - s;
  #pragma unroll
  for (int j = 0; j < 7; ++j){
    int idx = base+j;
    if (idx < NB){ int st = run + loc[j]; seg[c*(NB+1)+idx] = st; cur[idx] = st; }
  }
  if (tid == 0) seg[c*(NB+1)+NB] = CHUNK;
  __syncthreads();
  for (int i = tid; i < CHUNK; i += 256){
    const uint ss = (uint)src[e0+i], dd = (uint)dst[e0+i];
    const int p = atomicAdd(&cur[dd >> 6], 1);
    priv[(size_t)c*CHUNK + p] = (ss << 6) | (dd & 63u);
  }
}

// per bucket: scatter chunk-private edges into dst-node-sorted col via rp cursors
__global__ __launch_bounds__(256) void k_gathE2(const uint* __restrict__ priv, const int* __restrict__ seg,
                                                const int* __restrict__ rp, int* __restrict__ col){
  __shared__ int cur[64];
  const int b = blockIdx.x, tid = threadIdx.x;
  const int n0 = b * 64;
  if (tid < 64){
    const int idx = n0 + tid;
    cur[tid] = rp[(idx < NN) ? idx : NN];
  }
  __syncthreads();
  const int c = tid;
  const int s0 = seg[c*(NB+1) + b], s1 = seg[c*(NB+1) + b + 1];
  const size_t pbase = (size_t)c*CHUNK;
  for (int i = s0; i < s1; ++i){
    const uint e = priv[pbase + i];
    const int p = atomicAdd(&cur[e & 63u], 1);
    col[p] = (int)(e >> 6);
  }
}

// weights -> bf16 in per-lane MFMA fragment layout:
// frag id = q*16 + nr*2 + ks ; wimg[frag][lane*8+j] = W[col][k]
//   col = nr*16+(lane&15), k = q*64+ks*32+(lane>>4)*8+j
__global__ __launch_bounds__(256) void k_wprep(const float* __restrict__ sW, const float* __restrict__ bW,
                                               ushort* __restrict__ wimg){
  int idx = blockIdx.x*256 + threadIdx.x;
  if (idx >= NL*WSTRIDE) return;
  const int j    = idx & 7;
  const int lane = (idx >> 3) & 63;
  const int ks   = (idx >> 9) & 1;
  const int nr   = (idx >> 10) & 7;
  const int qq   = (idx >> 13) % NKS;
  const int l    = idx / (NKS << 13);
  const int colc = nr*16 + (lane & 15);
  const int kg   = qq*64 + ks*32 + (lane >> 4)*8 + j;
  const float v  = (kg < KSPL) ? sW[((size_t)l*FEAT + colc)*KSPL + kg]
                               : bW[((size_t)l*FEAT + colc)*FEAT + (kg - KSPL)];
  wimg[idx] = f2bf(v);
}

// ---------------- FKAN transform: single x-tile in LDS, inline LN/silu, 2-deep B prefetch ----------------
// output hprime in fp8 e4m3 (OCP), 128 B per node row
template <typename TIn>
__global__ __launch_bounds__(128) void k_fkan(
    const TIn* __restrict__ xin,            // [NN][128] fp32 or bf16(ushort)
    const ushort* __restrict__ wimg,        // this layer's fragment image (L2-resident)
    const float* __restrict__ ln_s, const float* __restrict__ ln_b,
    const float* __restrict__ sb, const float* __restrict__ bb,
    const float* __restrict__ dinv,
    unsigned char* __restrict__ hprime)
{
  __shared__ char xb[BM*256];        // x bf16 [32][128], xor-swizzled rows  (8 KB)
  __shared__ float lnS[128], lnB[128], sbias[128];

  const int tid  = threadIdx.x;
  const int lane = tid & 63, wv = tid >> 6;
  const int node0 = blockIdx.x * BM;   // NN % BM == 0: no guards anywhere

  lnS[tid] = ln_s[tid]; lnB[tid] = ln_b[tid]; sbias[tid] = sb[tid] + bb[tid];

  // ---- LN stats phase: 4 threads per node, 32 feats each; stage bf16 x in LDS ----
  const int lm = tid >> 2, part = tid & 3;
  const int node = node0 + lm;
  const uint swl = ((uint)(lm & 7)) << 4;
  char* xrow_w = xb + lm*256;
  float s1 = 0.f, s2 = 0.f;
  if constexpr (sizeof(TIn) == 4){
    const float4* xr = (const float4*)((const float*)xin + (size_t)node*FEAT + part*32);
    #pragma unroll
    for (int j = 0; j < 4; ++j){
      const float4 a = xr[2*j], b = xr[2*j+1];
      s1 += a.x+a.y+a.z+a.w + b.x+b.y+b.z+b.w;
      s2 += a.x*a.x+a.y*a.y+a.z*a.z+a.w*a.w + b.x*b.x+b.y*b.y+b.z*b.z+b.w*b.w;
      uintx4 pk;
      pk.x = pkbf(a.x, a.y); pk.y = pkbf(a.z, a.w);
      pk.z = pkbf(b.x, b.y); pk.w = pkbf(b.z, b.w);
      *(uintx4*)(xrow_w + (((uint)(part*64 + j*16)) ^ swl)) = pk;
    }
  } else {
    const uintx4* xr = (const uintx4*)((const ushort*)xin + (size_t)node*FEAT + part*32);
    #pragma unroll
    for (int j = 0; j < 4; ++j){
      const uintx4 v = xr[j];
      #pragma unroll
      for (int w = 0; w < 4; ++w){
        const float f0 = bf2f((ushort)(v[w] & 0xffff)), f1 = bf2f((ushort)(v[w] >> 16));
        s1 += f0 + f1; s2 += f0*f0 + f1*f1;
      }
      *(uintx4*)(xrow_w + (((uint)(part*64 + j*16)) ^ swl)) = v;
    }
  }
  s1 += __shfl_xor(s1, 1); s2 += __shfl_xor(s2, 1);
  s1 += __shfl_xor(s1, 2); s2 += __shfl_xor(s2, 2);
  const float mean = s1 * (1.f/128.f);
  const float var  = s2 * (1.f/128.f) - mean*mean;
  const float rsv  = rsqrtf(var + 1e-5f);
  __syncthreads();                       // xb + lnS/lnB/sbias ready -- only barrier

  // ---- MFMA K-loop: wave owns rows wv*16..+15, all 128 cols ----
  const int l15 = lane & 15, l4h = lane >> 4;
  const int row = wv*16 + l15;
  const uint swz = ((uint)(row & 7)) << 4;
  const char* xrow = xb + row*256;
  // fetch this row's LN stats from the thread that computed them (lane l15*4)
  const float mrow = __shfl(mean, (lane & 15) << 2);
  const float rrow = __shfl(rsv,  (lane & 15) << 2);

  floatx4 acc[8];
  #pragma unroll
  for (int nr = 0; nr < 8; ++nr){ floatx4 z4 = {0.f,0.f,0.f,0.f}; acc[nr] = z4; }

  const short8* w8 = (const short8*)wimg;

  auto afrag = [&](int sp)->short8 {
    const int q = sp >> 1, ks = sp & 1;
    if (q < 8){
      const int f0 = q*16 + ks*8 + l4h*2;
      const uint xx = *(const uint*)(xrow + (((uint)(f0*2)) ^ swz));
      const float x0 = bf2f((ushort)(xx & 0xffff)), x1 = bf2f((ushort)(xx >> 16));
      const float2 ls = *(const float2*)(lnS + f0);
      const float2 lb = *(const float2*)(lnB + f0);
      const float z0 = (x0 - mrow)*rrow*ls.x + lb.x;
      const float z1 = (x1 - mrow)*rrow*ls.y + lb.y;
      float e0[4], e1[4];
      #pragma unroll
      for (int g = 0; g < 4; ++g){
        const float gc = -2.f + (4.f/3.f)*(float)g;
        const float t0 = (z0 - gc)*0.75f;
        const float t1 = (z1 - gc)*0.75f;
        e0[g] = __expf(-t0*t0);
        e1[g] = __expf(-t1*t1);
      }
      uintx4 pw;
      pw.x = pkbf(e0[0], e0[1]); pw.y = pkbf(e0[2], e0[3]);
      pw.z = pkbf(e1[0], e1[1]); pw.w = pkbf(e1[2], e1[3]);
      return __builtin_bit_cast(short8, pw);
    } else {
      const int f0 = (q - 8)*64 + ks*32 + l4h*8;
      const uintx4 xx = *(const uintx4*)(xrow + (((uint)(f0*2)) ^ swz));
      uintx4 pw;
      #pragma unroll
      for (int w = 0; w < 4; ++w){
        const float x0 = bf2f((ushort)(xx[w] & 0xffff)), x1 = bf2f((ushort)(xx[w] >> 16));
        pw[w] = pkbf(fsilu(x0), fsilu(x1));
      }
      return __builtin_bit_cast(short8, pw);
    }
  };

  short8 b0[8], b1[8];
  #pragma unroll
  for (int nr = 0; nr < 8; ++nr) b0[nr] = w8[(size_t)(nr*2)*64 + lane];   // sp=0

  #pragma unroll
  for (int sp = 0; sp < 20; sp += 2){
    {   // prefetch sp+1 into b1
      const int q1 = (sp + 1) >> 1, ks1 = (sp + 1) & 1;
      #pragma unroll
      for (int nr = 0; nr < 8; ++nr) b1[nr] = w8[(size_t)(q1*16 + nr*2 + ks1)*64 + lane];
    }
    {
      const short8 af = afrag(sp);
      #pragma unroll
      for (int nr = 0; nr < 8; ++nr)
        acc[nr] = __builtin_amdgcn_mfma_f32_16x16x32_bf16(af, b0[nr], acc[nr], 0, 0, 0);
    }
    if (sp + 2 < 20){   // prefetch sp+2 into b0
      const int q2 = (sp + 2) >> 1, ks2 = (sp + 2) & 1;
      #pragma unroll
      for (int nr = 0; nr < 8; ++nr) b0[nr] = w8[(size_t)(q2*16 + nr*2 + ks2)*64 + lane];
    }
    {
      const short8 af = afrag(sp + 1);
      #pragma unroll
      for (int nr = 0; nr < 8; ++nr)
        acc[nr] = __builtin_amdgcn_mfma_f32_16x16x32_bf16(af, b1[nr], acc[nr], 0, 0, 0);
    }
  }

  // ---- epilogue: h' = dinv * (acc + bias), fp8 e4m3 store ----
  const int rbase = node0 + wv*16 + l4h*4;
  float dvv[4];
  #pragma unroll
  for (int j = 0; j < 4; ++j) dvv[j] = dinv[rbase + j];
  #pragma unroll
  for (int nr = 0; nr < 8; ++nr){
    const int cf = nr*16 + l15;
    const float sv = sbias[cf];
    #pragma unroll
    for (int j = 0; j < 4; ++j){
      const float val = dvv[j]*(acc[nr][j] + sv);
      const uint pk = (uint)__builtin_amdgcn_cvt_pk_fp8_f32(val, val, 0, false);
      hprime[(size_t)(rbase + j)*FEAT + cf] = (unsigned char)(pk & 0xFFu);
    }
  }
}

// ---------------- CSR aggregation: 2 dst per wave (32-lane halves), fp8 row gathers ----------------
__global__ __launch_bounds__(256) void k_aggD(
    const unsigned char* __restrict__ hprime, const int* __restrict__ rp,
    const int* __restrict__ col, const float* __restrict__ dinv,
    const float* __restrict__ gb, ushort* __restrict__ xout)
{
  const int wv = threadIdx.x >> 6, lane = threadIdx.x & 63;
  const int half = lane >> 5, li = lane & 31;
  const int d = blockIdx.x*8 + wv*2 + half;   // NN = 12500*8 exactly
  const uint* h8 = (const uint*)hprime;       // row = 32 uints (4 fp8 per lane = 4 feats)

  const uint v = h8[(size_t)d*32 + li];
  floatx2 vlo = __builtin_amdgcn_cvt_pk_f32_fp8(v, false);
  floatx2 vhi = __builtin_amdgcn_cvt_pk_f32_fp8(v, true);
  float a0 = vlo[0], a1 = vlo[1], a2 = vhi[0], a3 = vhi[1];

  const int j0 = rp[d], j1 = rp[d+1];
  int j = j0;
  for (; j + 7 < j1; j += 8){
    uint w[8];
    #pragma unroll
    for (int u = 0; u < 8; ++u) w[u] = h8[(size_t)col[j+u]*32 + li];
    #pragma unroll
    for (int u = 0; u < 8; ++u){
      const floatx2 lo = __builtin_amdgcn_cvt_pk_f32_fp8(w[u], false);
      const floatx2 hi = __builtin_amdgcn_cvt_pk_f32_fp8(w[u], true);
      a0 += lo[0]; a1 += lo[1]; a2 += hi[0]; a3 += hi[1];
    }
  }
  for (; j + 3 < j1; j += 4){
    uint w[4];
    #pragma unroll
    for (int u = 0; u < 4; ++u) w[u] = h8[(size_t)col[j+u]*32 + li];
    #pragma unroll
    for (int u = 0; u < 4; ++u){
      const floatx2 lo = __builtin_amdgcn_cvt_pk_f32_fp8(w[u], false);
      const floatx2 hi = __builtin_amdgcn_cvt_pk_f32_fp8(w[u], true);
      a0 += lo[0]; a1 += lo[1]; a2 += hi[0]; a3 += hi[1];
    }
  }
  for (; j < j1; ++j){
    const uint w = h8[(size_t)col[j]*32 + li];
    const floatx2 lo = __builtin_amdgcn_cvt_pk_f32_fp8(w, false);
    const floatx2 hi = __builtin_amdgcn_cvt_pk_f32_fp8(w, true);
    a0 += lo[0]; a1 += lo[1]; a2 += hi[0]; a3 += hi[1];
  }

  const float dv = dinv[d];
  const float4 b4 = *(const float4*)(gb + li*4);
  a0 = fsilu(dv*a0 + b4.x);
  a1 = fsilu(dv*a1 + b4.y);
  a2 = fsilu(dv*a2 + b4.z);
  a3 = fsilu(dv*a3 + b4.w);
  uint2 o;
  o.x = (uint)f2bf(a0) | ((uint)f2bf(a1) << 16);
  o.y = (uint)f2bf(a2) | ((uint)f2bf(a3) << 16);
  ((uint2*)xout)[(size_t)d*32 + li] = o;
}

// ---------------- pooling (sorted batch) ----------------
__global__ __launch_bounds__(128) void k_pool(const ushort* __restrict__ x,
                                              const int* __restrict__ batch,
                                              float* __restrict__ pooled,
                                              float* __restrict__ cnt, int n){
  const int f = threadIdx.x;
  const int start = blockIdx.x * 64;
  const int end   = min(start + 64, n);
  if (start >= end) return;
  int cur = batch[start];
  float acc = 0.f, c = 0.f;
  for (int i = start; i < end; ++i){
    const int b = batch[i];
    if (b != cur){
      atomicAdd(&pooled[(size_t)cur*FEAT + f], acc);
      if (f == 0) atomicAdd(&cnt[cur], c);
      cur = b; acc = 0.f; c = 0.f;
    }
    acc += bf2f(x[(size_t)i*FEAT + f]);
    c += 1.f;
  }
  atomicAdd(&pooled[(size_t)cur*FEAT + f], acc);
  if (f == 0) atomicAdd(&cnt[cur], c);
}

__global__ __launch_bounds__(128) void k_pool_div(float* __restrict__ pooled,
                                                  const float* __restrict__ cnt){
  const int g = blockIdx.x, f = threadIdx.x;
  pooled[(size_t)g*FEAT + f] /= fmaxf(cnt[g], 1.f);
}

// ---------------- readout FastKAN (128 -> 10) + log_softmax ----------------
__global__ __launch_bounds__(128) void k_readout(const float* __restrict__ pooled,
    const float* __restrict__ ln_s, const float* __restrict__ ln_b,
    const float* __restrict__ sW, const float* __restrict__ sb,
    const float* __restrict__ bW, const float* __restrict__ bb,
    float* __restrict__ out){
  __shared__ float cb[KSPL + FEAT];
  __shared__ float wred[2][2];
  __shared__ float outv[NCLS];
  const int tid = threadIdx.x, lane = tid & 63, wave = tid >> 6;
  const int g = blockIdx.x;

  const float xvv = pooled[(size_t)g*FEAT + tid];
  float s1 = xvv, s2 = xvv*xvv;
  #pragma unroll
  for (int off = 32; off; off >>= 1){ s1 += __shfl_down(s1, off); s2 += __shfl_down(s2, off); }
  if (lane == 0){ wred[wave][0] = s1; wred[wave][1] = s2; }
  __syncthreads();
  const float m   = (wred[0][0] + wred[1][0]) * (1.f/FEAT);
  const float var = (wred[0][1] + wred[1][1]) * (1.f/FEAT) - m*m;
  const float rs  = rsqrtf(var + 1e-5f);
  const float z   = (xvv - m) * rs * ln_s[tid] + ln_b[tid];
  #pragma unroll
  for (int gg = 0; gg < GQ; ++gg){
    const float t = (z - (-2.f + (4.f/3.f)*(float)gg)) * 0.75f;
    cb[tid*GQ + gg] = __expf(-t*t);
  }
  cb[KSPL + tid] = fsilu(xvv);
  __syncthreads();

  if (tid < NCLS){
    const float* wr = sW + (size_t)tid*KSPL;
    const float* br = bW + (size_t)tid*FEAT;
    float acc = sb[tid] + bb[tid];
    for (int k = 0; k < KSPL; ++k) acc += cb[k] * wr[k];
    for (int k = 0; k < FEAT; ++k) acc += cb[KSPL + k] * br[k];
    outv[tid] = acc;
  }
  __syncthreads();
  if (tid == 0){
    float mx = -1e30f;
    for (int o = 0; o < NCLS; ++o) mx = fmaxf(mx, outv[o]);
    float se = 0.f;
    for (int o = 0; o < NCLS; ++o) se += __expf(outv[o] - mx);
    const float lse = mx + logf(se);
    for (int o = 0; o < NCLS; ++o) out[(size_t)g*NCLS + o] = outv[o] - lse;
  }
}

extern "C" void kernel_launch(void* const* d_in, const int* in_sizes, int n_in,
                              void* d_out, int out_size, void* d_ws, size_t ws_size,
                              hipStream_t stream) {
  const float* x     = (const float*)d_in[0];
  const int*   edge  = (const int*)d_in[1];
  const int*   batch = (const int*)d_in[2];
  const float* ln_s  = (const float*)d_in[3];
  const float* ln_b  = (const float*)d_in[4];
  const float* sW    = (const float*)d_in[5];
  const float* sb    = (const float*)d_in[6];
  const float* bW    = (const float*)d_in[7];
  const float* bb    = (const float*)d_in[8];
  const float* gcn_b = (const float*)d_in[9];
  const float* ro_ln_s = (const float*)d_in[10];
  const float* ro_ln_b = (const float*)d_in[11];
  const float* ro_sW   = (const float*)d_in[12];
  const float* ro_sb   = (const float*)d_in[13];
  const float* ro_bW   = (const float*)d_in[14];
  const float* ro_bb   = (const float*)d_in[15];
  float* out = (float*)d_out;

  const int* src = edge;
  const int* dst = edge + NE;

  char* W = (char*)d_ws;
  size_t off = 0;
  auto alloc = [&](size_t bytes){ size_t r = off; off += (bytes + 1023) & ~((size_t)1023); return r; };
  float*  dinv   = (float*) (W + alloc((size_t)NN*4));
  ushort* wimg   = (ushort*)(W + alloc((size_t)NL*WSTRIDE*2));
  int*    hist   = (int*)   (W + alloc((size_t)NN*4));
  int*    rp     = (int*)   (W + alloc((size_t)(NN+1)*4));
  int*    tsum   = (int*)   (W + alloc((size_t)NT*4));
  int*    toff   = (int*)   (W + alloc((size_t)NT*4));
  uint*   priv   = (uint*)  (W + alloc((size_t)NE*4));
  int*    seg    = (int*)   (W + alloc((size_t)NCHUNK*(NB+1)*4));
  int*    col    = (int*)   (W + alloc((size_t)NE*4));
  unsigned char* hprime = (unsigned char*)(W + alloc((size_t)NN*FEAT));
  ushort* xcur   = (ushort*)(W + alloc((size_t)NN*FEAT*2));
  float*  pooled = (float*) (W + alloc((size_t)(NGR*FEAT + NGR)*4));
  float*  cnt    = pooled + NGR*FEAT;

  // degree norm + CSR build (layer-invariant)
  k_zero_i<<<(NN+255)/256, 256, 0, stream>>>(hist, NN);
  k_zero_f<<<(NGR*FEAT+NGR+255)/256, 256, 0, stream>>>(pooled, NGR*FEAT + NGR);
  k_hist<<<(NE+255)/256, 256, 0, stream>>>(dst, hist, NE);
  k_scan_a<<<NT, 256, 0, stream>>>(hist, tsum);
  k_scan_b<<<1, 128, 0, stream>>>(tsum, toff, rp + NN);
  k_scan_c<<<NT, 256, 0, stream>>>(hist, toff, rp, dinv);
  k_binA<<<NCHUNK, 256, 0, stream>>>(src, dst, priv, seg);
  k_gathE2<<<NB, 256, 0, stream>>>(priv, seg, rp, col);
  k_wprep<<<(NL*WSTRIDE + 255)/256, 256, 0, stream>>>(sW, bW, wimg);

  const int fkan_grid = NN / BM;
  for (int l = 0; l < NL; ++l){
    const ushort* wl = wimg + (size_t)l*WSTRIDE;
    if (l == 0)
      k_fkan<float><<<fkan_grid, 128, 0, stream>>>(x, wl,
          ln_s + l*FEAT, ln_b + l*FEAT, sb + l*FEAT, bb + l*FEAT, dinv, hprime);
    else
      k_fkan<ushort><<<fkan_grid, 128, 0, stream>>>(xcur, wl,
          ln_s + l*FEAT, ln_b + l*FEAT, sb + l*FEAT, bb + l*FEAT, dinv, hprime);
    k_aggD<<<NN/8, 256, 0, stream>>>(hprime, rp, col, dinv, gcn_b + l*FEAT, xcur);
  }

  k_pool<<<(NN+63)/64, 128, 0, stream>>>(xcur, batch, pooled, cnt, NN);
  k_pool_div<<<NGR, 128, 0, stream>>>(pooled, cnt);
  k_readout<<<NGR, 128, 0, stream>>>(pooled, ro_ln_s, ro_ln_b,
                                     ro_sW, ro_sb, ro_bW, ro_bb, out);
}